// Round 16
// baseline (1071.904 us; speedup 1.0000x reference)
//
#include <hip/hip_runtime.h>
#include <hip/hip_bf16.h>

#define NN 50000
#define NE 800000
#define NA (NE + NN)
#define NH 8
#define NC 16
#define ND 128
#define NHID 64
#define NSH 64
#define NOUT 40
#define BN_EPS 1e-5

#define WOFF (NN * NOUT)
#define LOFF (WOFF + NE)
#define NIN 27
#define NCV 22

static inline int ceil_div(int a, int b) { return (a + b - 1) / b; }

typedef __hip_bfloat16 bf16;
__device__ inline float b2f(bf16 v) { return __bfloat162float(v); }

struct Ptrs { const void* p[NIN]; int n[NIN]; };
struct ConvTab { int src[NCV]; int dstOff[NCV]; int n[NCV]; };

__global__ void sent_k(float* out, float v) { out[0] = v; }

// ---------- dtype detection (fp32 vs bf16; int32 vs int64) ----------
__global__ __launch_bounds__(64) void detect_k(Ptrs P, int* flags) {
    int b = blockIdx.x, lane = threadIdx.x;
    const void* p = P.p[b];
    int n = P.n[b];
    if (b == 1) {
        const int* w = (const int*)p;
        int m = n < 256 ? n : 256;
        int oddNz = 0;
        for (int i = lane; i < m; i += 64)
            if ((i & 1) && w[i] != 0) oddNz = 1;
        unsigned long long any = __ballot(oddNz);
        if (lane == 0) flags[1] = (any == 0ULL) ? 1 : 0;   // 1 => int64
        return;
    }
    int m = n < 256 ? n : 256;
    const bf16* hb = (const bf16*)p;
    int impl = 0, evenNz = 0, oddNz = 0;
    for (int i = lane; i < m; i += 64) {
        float v = b2f(hb[i]);
        bool bad = !isfinite(v) || fabsf(v) > 64.0f || (v != 0.0f && fabsf(v) < 1e-6f);
        if (bad) impl++;
        if (v != 0.0f) { if (i & 1) oddNz = 1; else evenNz = 1; }
    }
#pragma unroll
    for (int off = 32; off > 0; off >>= 1) impl += __shfl_down(impl, off, 64);
    unsigned long long be = __ballot(evenNz), bo = __ballot(oddNz);
    if (lane == 0) {
        int thresh = (m >= 8) ? (m / 8) : 1;
        int isF32 = 0;
        if (impl >= thresh) isF32 = 1;
        else if (be == 0ULL && bo != 0ULL) isF32 = 1;
        flags[b] = isF32;
    }
}

__global__ __launch_bounds__(256) void conv_f_k(const void* __restrict__ src,
                                                const int* __restrict__ flags, int fi,
                                                float* __restrict__ dst, int n) {
    int i = blockIdx.x * 256 + threadIdx.x;
    if (i >= n) return;
    dst[i] = flags[fi] ? ((const float*)src)[i] : b2f(((const bf16*)src)[i]);
}

// fused conversion of all small weight tensors (one block per tensor)
__global__ __launch_bounds__(256) void conv_all_k(Ptrs P, ConvTab T,
                                                  const int* __restrict__ flags,
                                                  float* __restrict__ wa) {
    int b = blockIdx.x;
    const void* src = P.p[T.src[b]];
    int isf = flags[T.src[b]];
    float* dst = wa + T.dstOff[b];
    int n = T.n[b];
    for (int i = threadIdx.x; i < n; i += 256)
        dst[i] = isf ? ((const float*)src)[i] : b2f(((const bf16*)src)[i]);
}

// repack Ws1 [64][256] -> fused [128][128]
__global__ __launch_bounds__(256) void repack_ws1_k(const float* __restrict__ s,
                                                    float* __restrict__ d) {
    int id = blockIdx.x * 256 + threadIdx.x;
    if (id >= 128 * 128) return;
    int m = id >> 7, k = id & 127;
    d[id] = (m < 64) ? s[m * 256 + k] : s[(m - 64) * 256 + 128 + k];
}

__global__ __launch_bounds__(256) void conv_i_k(const void* __restrict__ src,
                                                const int* __restrict__ flags,
                                                int* __restrict__ dst, int n) {
    int i = blockIdx.x * 256 + threadIdx.x;
    if (i >= n) return;
    const int* s = (const int*)src;
    dst[i] = flags[1] ? s[2 * i] : s[i];
}

__global__ __launch_bounds__(256) void check_k(const int* __restrict__ ei, int* err) {
    int i = blockIdx.x * 256 + threadIdx.x;
    if (i < 2 * NE && (unsigned)ei[i] >= NN) atomicOr(err, 1);
}
__global__ void finalize_k(const int* err, float* out) {
    if (*err) out[0] = 800.0f;
}

// ---------- ordered-key mapping for fp64 atomic max ----------
__device__ inline unsigned long long d2key(double v) {
    unsigned long long b = __double_as_longlong(v);
    return (b & 0x8000000000000000ULL) ? ~b : (b | 0x8000000000000000ULL);
}
__device__ inline double key2d(unsigned long long k) {
    return (k & 0x8000000000000000ULL) ? __longlong_as_double(k & 0x7fffffffffffffffULL)
                                       : __longlong_as_double(~k);
}

// ---------- CSR build ----------
__global__ __launch_bounds__(256) void deg_dst_k(const int* __restrict__ ei, int* deg) {
    int e = blockIdx.x * 256 + threadIdx.x;
    if (e >= NA) return;
    int d = (e < NE) ? ei[NE + e] : e - NE;
    if ((unsigned)d < NN) atomicAdd(&deg[d], 1);
}
__global__ __launch_bounds__(256) void deg_row_k(const int* __restrict__ ei, int* deg) {
    int e = blockIdx.x * 256 + threadIdx.x;
    if (e >= NE) return;
    int r = ei[e];
    if ((unsigned)r < NN) atomicAdd(&deg[r], 1);
}

// ---------- hierarchical exclusive scan ----------
__global__ __launch_bounds__(256) void scan1_k(const int* __restrict__ deg,
                                               int* __restrict__ offs,
                                               int* __restrict__ bsums, int n) {
    __shared__ int sh[256];
    int i = blockIdx.x * 256 + threadIdx.x;
    int v = (i < n) ? deg[i] : 0;
    sh[threadIdx.x] = v;
    __syncthreads();
    int acc = v;
    for (int off = 1; off < 256; off <<= 1) {
        int t = (threadIdx.x >= off) ? sh[threadIdx.x - off] : 0;
        __syncthreads();
        acc += t;
        sh[threadIdx.x] = acc;
        __syncthreads();
    }
    if (i < n) offs[i] = acc - v;
    if (threadIdx.x == 255) bsums[blockIdx.x] = acc;
}
__global__ __launch_bounds__(256) void scan2_k(int* __restrict__ bsums, int nb) {
    __shared__ int sh[256];
    int t = threadIdx.x;
    int v = (t < nb) ? bsums[t] : 0;
    sh[t] = v;
    __syncthreads();
    int acc = v;
    for (int off = 1; off < 256; off <<= 1) {
        int x = (t >= off) ? sh[t - off] : 0;
        __syncthreads();
        acc += x;
        sh[t] = acc;
        __syncthreads();
    }
    if (t < nb) bsums[t] = acc - v;
    if (t == nb - 1) bsums[nb] = acc;
}
__global__ __launch_bounds__(256) void scan3_k(int* __restrict__ offs,
                                               const int* __restrict__ bsums, int n, int nb) {
    int i = blockIdx.x * 256 + threadIdx.x;
    if (i < n) offs[i] += bsums[blockIdx.x];
    else if (i == n) offs[n] = bsums[nb];
}
__global__ __launch_bounds__(256) void copy_k(const int* __restrict__ a, int* __restrict__ b,
                                              int n) {
    int i = blockIdx.x * 256 + threadIdx.x;
    if (i < n) b[i] = a[i];
}

__global__ __launch_bounds__(256) void scat_dst_k(const int* __restrict__ ei, int* cur,
                                                  int* __restrict__ entS,
                                                  int* __restrict__ entD) {
    int e = blockIdx.x * 256 + threadIdx.x;
    if (e >= NA) return;
    int s, d;
    if (e < NE) { s = ei[e]; d = ei[NE + e]; }
    else        { s = d = e - NE; }
    if ((unsigned)s >= NN || (unsigned)d >= NN) return;
    int pos = atomicAdd(&cur[d], 1);
    entS[pos] = s;
    entD[pos] = d;
}
__global__ __launch_bounds__(256) void scat_row_k(const int* __restrict__ ei, int* cur,
                                                  int* __restrict__ entc,
                                                  int* __restrict__ ente) {
    int e = blockIdx.x * 256 + threadIdx.x;
    if (e >= NE) return;
    int r = ei[e], c = ei[NE + e];
    if ((unsigned)r >= NN || (unsigned)c >= NN) return;
    int pos = atomicAdd(&cur[r], 1);
    entc[pos] = c;
    ente[pos] = e;
}

// ---------- tiled GEMM: hybrid accumulation (fp32 16-step K-chunks -> fp64) ----------
template <int M, int K, int TC, bool ADD2, int XBN>
__global__ __launch_bounds__(256) void gemm_k(const float* __restrict__ X,
                                              const float* __restrict__ X2,
                                              const float2* __restrict__ ssX,
                                              const float* __restrict__ W, int wstride,
                                              const float* __restrict__ bias,
                                              float* __restrict__ Y, int nrows) {
    constexpr int KT = 32;
    constexpr int TR = 256 / TC;
    constexpr int ROWS = TR * 4;
    __shared__ float Ws[KT][M + 4];
    __shared__ float Xs[ROWS][KT + 4];

    const int t = threadIdx.x;
    const int lane = t & 63, wv = t >> 6;
    const int row0 = blockIdx.x * ROWS;

    double acc[4][4];
#pragma unroll
    for (int i = 0; i < 4; ++i)
#pragma unroll
        for (int j = 0; j < 4; ++j) acc[i][j] = 0.0;

    for (int k0 = 0; k0 < K; k0 += KT) {
        {
            const int mi = lane >> 3, ki = lane & 7;
            for (int b = wv; b < (M / 8) * (KT / 8); b += 4) {
                int bm = b % (M / 8), bk = b / (M / 8);
                int m = bm * 8 + mi, kk = bk * 8 + ki;
                Ws[kk][m] = W[(size_t)m * wstride + k0 + kk];
            }
        }
        for (int idx = t; idx < ROWS * KT; idx += 256) {
            int r = idx / KT, kk = idx % KT;
            int row = row0 + r;
            float v = 0.0f;
            if (row < nrows) {
                v = X[(size_t)row * K + k0 + kk];
                if (ADD2) v += X2[(size_t)row * K + k0 + kk];
                if (XBN) {
                    float2 s = ssX[k0 + kk];
                    v = v * s.x + s.y;
                    if (XBN == 1) v = v > 0.0f ? v : expm1f(v);
                    else          v = v > 0.0f ? v : 0.0f;
                }
            }
            Xs[r][kk] = v;
        }
        __syncthreads();

        if (t < TR * TC) {
            const int c0 = (t % TC) * 4;
            const int r0 = (t / TC) * 4;
            float facc[4][4];
#pragma unroll
            for (int i = 0; i < 4; ++i)
#pragma unroll
                for (int j = 0; j < 4; ++j) facc[i][j] = 0.0f;
#pragma unroll 4
            for (int kk = 0; kk < KT; ++kk) {
                float4 w = *(const float4*)&Ws[kk][c0];
#pragma unroll
                for (int i = 0; i < 4; ++i) {
                    float x = Xs[r0 + i][kk];
                    facc[i][0] += x * w.x;
                    facc[i][1] += x * w.y;
                    facc[i][2] += x * w.z;
                    facc[i][3] += x * w.w;
                }
                if ((kk & 15) == 15) {
#pragma unroll
                    for (int i = 0; i < 4; ++i)
#pragma unroll
                        for (int j = 0; j < 4; ++j) {
                            acc[i][j] += (double)facc[i][j];
                            facc[i][j] = 0.0f;
                        }
                }
            }
        }
        __syncthreads();
    }

    if (t < TR * TC) {
        const int c0 = (t % TC) * 4;
        const int r0 = (t / TC) * 4;
#pragma unroll
        for (int i = 0; i < 4; ++i) {
            int row = row0 + r0 + i;
            if (row >= nrows) break;
#pragma unroll
            for (int j = 0; j < 4; ++j) {
                double v = acc[i][j];
                if (bias) v += (double)bias[c0 + j];
                Y[(size_t)row * M + c0 + j] = (float)v;
            }
        }
    }
}

// ---------- attention scores + per-head global max ----------
__global__ __launch_bounds__(256) void att_scores_k(const float* __restrict__ h,
                                                    const float* __restrict__ asw,
                                                    const float* __restrict__ adw,
                                                    double* __restrict__ a_src,
                                                    double* __restrict__ a_dst,
                                                    unsigned long long* __restrict__ keyM) {
    __shared__ double shS[256], shD[256];
    int id = blockIdx.x * 256 + threadIdx.x;
    double s = -1e300, d = -1e300;
    if (id < NN * NH) {
        int n = id / NH, hh = id % NH;
        const float* hp = h + (size_t)n * ND + hh * NC;
        s = 0.0; d = 0.0;
#pragma unroll
        for (int c = 0; c < NC; ++c) {
            double v = (double)hp[c];
            s += v * (double)asw[hh * NC + c];
            d += v * (double)adw[hh * NC + c];
        }
        a_src[id] = s;
        a_dst[id] = d;
    }
    shS[threadIdx.x] = s;
    shD[threadIdx.x] = d;
    __syncthreads();
    if (threadIdx.x < NH) {
        double mS = -1e300, mD = -1e300;
        for (int k = threadIdx.x; k < 256; k += NH) {
            if (shS[k] > mS) mS = shS[k];
            if (shD[k] > mD) mD = shD[k];
        }
        atomicMax(&keyM[threadIdx.x], d2key(mS));
        atomicMax(&keyM[NH + threadIdx.x], d2key(mD));
    }
}

// ---------- edge-parallel exp (fp32 expf; x computed fp64) ----------
__global__ __launch_bounds__(256) void edge_exp_k(const int* __restrict__ entS,
                                                  const int* __restrict__ entD,
                                                  const double* __restrict__ a_src,
                                                  const double* __restrict__ a_dst,
                                                  const unsigned long long* __restrict__ keyM,
                                                  float* __restrict__ expv) {
    int id = blockIdx.x * 256 + threadIdx.x;
    if (id >= NA * NH) return;
    int i = id >> 3, hh = id & 7;
    int s = entS[i], d = entD[i];
    double x = a_src[(size_t)s * NH + hh] + a_dst[(size_t)d * NH + hh];
    x = x > 0.0 ? x : 0.2 * x;
    double M = key2d(keyM[hh]) + key2d(keyM[NH + hh]);
    if (M < 0.0) M = 0.0;
    expv[id] = expf((float)(x - M));
}

// ---------- GAT gather: wave per dst, float2 feature packing, unroll-4 ----------
// Lane owns features (2l, 2l+1) -> same head hh=l>>3; one float2 h-load + one e-load per
// neighbor. Per-feature accumulation order unchanged -> bit-identical.
__global__ __launch_bounds__(256) void gat_gather_k(const int* __restrict__ offs,
                                                    const int* __restrict__ ent,
                                                    const float* __restrict__ h,
                                                    const float* __restrict__ expv,
                                                    float* __restrict__ outb) {
    int wv = (blockIdx.x * 256 + threadIdx.x) >> 6;
    int lane = threadIdx.x & 63;
    if (wv >= NN) return;
    const int s0 = offs[wv], s1 = offs[wv + 1];
    const int hh = lane >> 3;                       // head of features 2l, 2l+1
    double acc0 = 0.0, acc1 = 0.0, den = 0.0;
    int i = s0;
    for (; i + 4 <= s1; i += 4) {
        int sA = ent[i], sB = ent[i + 1], sC = ent[i + 2], sD = ent[i + 3];
        float eA = expv[(size_t)(i + 0) * NH + hh];
        float eB = expv[(size_t)(i + 1) * NH + hh];
        float eC = expv[(size_t)(i + 2) * NH + hh];
        float eD = expv[(size_t)(i + 3) * NH + hh];
        float2 a = *(const float2*)&h[(size_t)sA * ND + 2 * lane];
        float2 b = *(const float2*)&h[(size_t)sB * ND + 2 * lane];
        float2 c = *(const float2*)&h[(size_t)sC * ND + 2 * lane];
        float2 d = *(const float2*)&h[(size_t)sD * ND + 2 * lane];
        acc0 += (double)a.x * eA; acc1 += (double)a.y * eA; den += (double)eA;
        acc0 += (double)b.x * eB; acc1 += (double)b.y * eB; den += (double)eB;
        acc0 += (double)c.x * eC; acc1 += (double)c.y * eC; den += (double)eC;
        acc0 += (double)d.x * eD; acc1 += (double)d.y * eD; den += (double)eD;
    }
    for (; i < s1; ++i) {
        int s = ent[i];
        float e = expv[(size_t)i * NH + hh];
        float2 a = *(const float2*)&h[(size_t)s * ND + 2 * lane];
        acc0 += (double)a.x * e; acc1 += (double)a.y * e; den += (double)e;
    }
    double inv = den > 0.0 ? 1.0 / den : 0.0;
    float2 o = make_float2((float)(acc0 * inv), (float)(acc1 * inv));
    *(float2*)&outb[(size_t)wv * ND + 2 * lane] = o;
}

// ---------- one-pass BN stats ----------
template <int M>
__global__ __launch_bounds__(256) void bn_stats1_k(const float* __restrict__ X,
                                                   double* __restrict__ stats, int rpb) {
    constexpr int G = 256 / M;
    __shared__ double sh0[256], sh1[256];
    int f = threadIdx.x % M, g = threadIdx.x / M;
    int r0 = blockIdx.x * rpb;
    int rend = r0 + rpb; if (rend > NN) rend = NN;
    double s = 0.0, s2 = 0.0;
    for (int r = r0 + g; r < rend; r += G) {
        double v = (double)X[(size_t)r * M + f];
        s += v;
        s2 += v * v;
    }
    sh0[threadIdx.x] = s;
    sh1[threadIdx.x] = s2;
    __syncthreads();
    if (g == 0) {
#pragma unroll
        for (int gg = 1; gg < G; ++gg) { s += sh0[gg * M + f]; s2 += sh1[gg * M + f]; }
        atomicAdd(&stats[f], s);
        atomicAdd(&stats[M + f], s2);
    }
}

template <int M>
__global__ void bn_fin_k(const double* __restrict__ stats,
                         const float* __restrict__ gamma, const float* __restrict__ beta,
                         float2* __restrict__ ss) {
    int f = threadIdx.x;
    if (f >= M) return;
    double mu = stats[f] / (double)NN;
    double var = stats[M + f] / (double)NN - mu * mu;
    if (var < 0.0) var = 0.0;
    double sc = (double)gamma[f] / sqrt(var + BN_EPS);
    ss[f] = make_float2((float)sc, (float)((double)beta[f] - mu * sc));
}

template <int M, int ACT>
__global__ __launch_bounds__(256) void bn_apply_ss_k(const float* __restrict__ X,
                                                     const float2* __restrict__ ss,
                                                     float* __restrict__ Y) {
    int id = blockIdx.x * 256 + threadIdx.x;
    if (id >= NN * M) return;
    float2 s = ss[id % M];
    float v = X[id] * s.x + s.y;
    if (ACT == 0) v = v > 0.0f ? v : expm1f(v);
    else          v = v > 0.0f ? v : 0.0f;
    Y[id] = v;
}

// ---------- edge logits: ROW-GROUPED, 16 lanes/edge, pr cached in registers ----------
// One wave per row r: pr float4s loaded once, reused across the row's edges (CSR order).
// Per-edge math/reduce identical to the flat version -> bit-identical outputs.
__global__ __launch_bounds__(256) void edge_logits_row_k(const int* __restrict__ offsR,
                                                         const int* __restrict__ entRc,
                                                         const int* __restrict__ entRe,
                                                         const float4* __restrict__ fused4,
                                                         const float4* __restrict__ bs14,
                                                         const float4* __restrict__ Ws24,
                                                         const float* __restrict__ bs2,
                                                         const void* __restrict__ graw,
                                                         const int* __restrict__ flags,
                                                         float* __restrict__ out) {
    int wv = (blockIdx.x * 256 + threadIdx.x) >> 6;   // row id
    int lane = threadIdx.x & 63;
    int g = lane & 15;                                // dim group
    int grp = lane >> 4;                              // edge slot 0..3
    if (wv >= NN) return;
    const int s0 = offsR[wv], s1 = offsR[wv + 1];
    if (s0 == s1) return;
    float4 a = fused4[(size_t)wv * 32 + g];           // pr part, cached for whole row
    float4 s1v = bs14[g];
    float4 w2 = Ws24[g];
    double b2 = (double)bs2[0];
    int isf = flags[2];
    for (int i = s0 + grp; i < s1; i += 4) {
        int c = entRc[i];
        int e = entRe[i];
        float4 b = fused4[(size_t)c * 32 + 16 + g];   // pc part
        double t0 = (double)a.x + (double)b.x + (double)s1v.x; t0 = t0 > 0.0 ? t0 : 0.0;
        double t1 = (double)a.y + (double)b.y + (double)s1v.y; t1 = t1 > 0.0 ? t1 : 0.0;
        double t2 = (double)a.z + (double)b.z + (double)s1v.z; t2 = t2 > 0.0 ? t2 : 0.0;
        double t3 = (double)a.w + (double)b.w + (double)s1v.w; t3 = t3 > 0.0 ? t3 : 0.0;
        double v = t0 * (double)w2.x + t1 * (double)w2.y + t2 * (double)w2.z
                 + t3 * (double)w2.w;
#pragma unroll
        for (int off = 8; off > 0; off >>= 1) v += __shfl_xor(v, off, 64);  // 16-lane group
        if (g == 0) {
            double L = v + b2;
            double g0, g1;
            if (isf) {
                const float* gp = (const float*)graw;
                g0 = (double)gp[2 * e]; g1 = (double)gp[2 * e + 1];
            } else {
                const bf16* gp = (const bf16*)graw;
                g0 = (double)b2f(gp[2 * e]); g1 = (double)b2f(gp[2 * e + 1]);
            }
            out[WOFF + e] = ((L + g1) > g0) ? 1.0f : 0.0f;   // argmax tie -> index 0
            out[LOFF + e] = (float)L;
        }
    }
}

// ---------- sparse agg gather: ballot-compaction + float2 packing + unroll-4 ----------
__global__ __launch_bounds__(256) void agg_gather_k(const int* __restrict__ offs,
                                                    const int* __restrict__ entc,
                                                    const int* __restrict__ ente,
                                                    const float* __restrict__ w,
                                                    const float* __restrict__ hb,
                                                    float* __restrict__ aggF) {
    __shared__ int selBuf[4][64];
    int wv = (blockIdx.x * 256 + threadIdx.x) >> 6;
    int lane = threadIdx.x & 63;
    int wloc = (threadIdx.x >> 6);
    if (wv >= NN) return;
    int* sel = selBuf[wloc];
    const int s0 = offs[wv], s1 = offs[wv + 1];
    double a0 = 0.0, a1 = 0.0;
    for (int base = s0; base < s1; base += 64) {
        int i = base + lane;
        int c = 0;
        bool keep = false;
        if (i < s1) {
            c = entc[i];
            keep = w[ente[i]] > 0.5f;
        }
        unsigned long long m = __ballot(keep);
        int cnt = __popcll(m);
        if (keep) {
            int pos = __popcll(m & ((1ULL << lane) - 1ULL));
            sel[pos] = c;
        }
        __builtin_amdgcn_wave_barrier();
        int j = 0;
        for (; j + 4 <= cnt; j += 4) {
            int cA = sel[j], cB = sel[j + 1], cC = sel[j + 2], cD = sel[j + 3];
            float2 hA = *(const float2*)&hb[(size_t)cA * ND + 2 * lane];
            float2 hB = *(const float2*)&hb[(size_t)cB * ND + 2 * lane];
            float2 hC = *(const float2*)&hb[(size_t)cC * ND + 2 * lane];
            float2 hD = *(const float2*)&hb[(size_t)cD * ND + 2 * lane];
            a0 += (double)hA.x; a1 += (double)hA.y;
            a0 += (double)hB.x; a1 += (double)hB.y;
            a0 += (double)hC.x; a1 += (double)hC.y;
            a0 += (double)hD.x; a1 += (double)hD.y;
        }
        for (; j < cnt; ++j) {
            int c2 = sel[j];
            float2 hv = *(const float2*)&hb[(size_t)c2 * ND + 2 * lane];
            a0 += (double)hv.x; a1 += (double)hv.y;
        }
        __builtin_amdgcn_wave_barrier();
    }
    float2 o = make_float2((float)a0, (float)a1);
    *(float2*)&aggF[(size_t)wv * ND + 2 * lane] = o;
}

// ---------- log-softmax (fp32) ----------
__global__ __launch_bounds__(256) void logsoftmax_k(const float* __restrict__ Y,
                                                    float* __restrict__ out) {
    int wid = (blockIdx.x * 256 + threadIdx.x) / 64;
    int lane = threadIdx.x & 63;
    if (wid >= NN) return;
    float v = (lane < NOUT) ? Y[(size_t)wid * NOUT + lane] : -1e30f;
    float m = v;
#pragma unroll
    for (int off = 32; off > 0; off >>= 1) {
        float o = __shfl_xor(m, off, 64);
        m = m > o ? m : o;
    }
    float ex = (lane < NOUT) ? expf(v - m) : 0.0f;
    float s = ex;
#pragma unroll
    for (int off = 32; off > 0; off >>= 1) s += __shfl_xor(s, off, 64);
    if (lane < NOUT) out[(size_t)wid * NOUT + lane] = v - m - logf(s);
}

extern "C" void kernel_launch(void* const* d_in, const int* in_sizes, int n_in,
                              void* d_out, int out_size, void* d_ws, size_t ws_size,
                              hipStream_t stream) {
    float* out = (float*)d_out;

    static const int EXPS[NIN] = {
        NN * 128, 2 * NE, 2 * NE, 16384, 128, 16384, 128, 128, 128, 128, 128,
        16384, 128, 128, 128, 128, 128, 16384, 64, 64, 1, 8192, 64, 64, 64, 2560, 40 };
    if (n_in != NIN) { sent_k<<<1, 1, 0, stream>>>(out, 700.0f); return; }
    if (out_size != NN * NOUT + 2 * NE) { sent_k<<<1, 1, 0, stream>>>(out, 600.0f); return; }
    for (int i = 0; i < NIN; ++i)
        if (in_sizes[i] != EXPS[i]) {
            sent_k<<<1, 1, 0, stream>>>(out, 1000.0f + 128.0f * i);
            return;
        }

    // ---- workspace layout ----
    char* W = (char*)d_ws;
    double* a_src = (double*)W;                      W += (size_t)NN * NH * 8;
    double* a_dst = (double*)W;                      W += (size_t)NN * NH * 8;
    double* stats = (double*)W;                      W += 256 * 8;
    unsigned long long* keyM = (unsigned long long*)W; W += 16 * 8;
    float2* ss = (float2*)W;                         W += 128 * 8;
    float* F1 = (float*)W;                           W += (size_t)NN * ND * 4;
    float* F2 = (float*)W;                           W += (size_t)NN * ND * 4;
    float* F3 = (float*)W;                           W += (size_t)NN * ND * 4;
    float* F4 = (float*)W;                           W += (size_t)NN * ND * 4;
    float* expv = (float*)W;                         W += (size_t)NA * NH * 4;
    float* wa = (float*)W;
    int off = 0;
    float* aW_res = wa + off; off += 16384;
    float* ab_res = wa + off; off += 128;
    float* aWg1 = wa + off; off += 16384;
    float* aas1 = wa + off; off += 128;
    float* aad1 = wa + off; off += 128;
    float* ag1  = wa + off; off += 128;
    float* abe1 = wa + off; off += 128;
    float* aWg2 = wa + off; off += 16384;
    float* aas2 = wa + off; off += 128;
    float* aad2 = wa + off; off += 128;
    float* ag2  = wa + off; off += 128;
    float* abe2 = wa + off; off += 128;
    float* aWs1 = wa + off; off += 16384;
    float* abs1 = wa + off; off += 64;
    float* aWs2 = wa + off; off += 64;
    float* abs2 = wa + off; off += 4;
    float* aWc1 = wa + off; off += 8192;
    float* abc1 = wa + off; off += 64;
    float* agc  = wa + off; off += 64;
    float* abec = wa + off; off += 64;
    float* aWc2 = wa + off; off += 2560;
    float* abc2 = wa + off; off += 40;
    float* aWs1f = wa + off; off += 16384;
    W = (char*)(wa + off);
    int* ei    = (int*)W;  W += (size_t)2 * NE * 4;
    int* offsG = (int*)W;  W += (size_t)(NN + 1) * 4;
    int* curG  = (int*)W;  W += (size_t)NN * 4;
    int* entG  = (int*)W;  W += (size_t)NA * 4;
    int* entD  = (int*)W;  W += (size_t)NA * 4;
    int* offsR = (int*)W;  W += (size_t)(NN + 1) * 4;
    int* curR  = (int*)W;  W += (size_t)NN * 4;
    int* entRc = (int*)W;  W += (size_t)NE * 4;
    int* entRe = (int*)W;  W += (size_t)NE * 4;
    int* bsums = (int*)W;  W += 260 * 4;
    int* flags = (int*)W;  W += 32 * 4;
    int* errflag = (int*)W; W += 4;
    if ((size_t)(W - (char*)d_ws) > ws_size) { sent_k<<<1, 1, 0, stream>>>(out, 900.0f); return; }

    const int NB = ceil_div(NN, 256);

    // ---- 0) detect & convert ----
    Ptrs P;
    for (int i = 0; i < NIN; ++i) { P.p[i] = d_in[i]; P.n[i] = in_sizes[i]; }
    detect_k<<<NIN, 64, 0, stream>>>(P, flags);
    conv_i_k<<<ceil_div(2 * NE, 256), 256, 0, stream>>>(d_in[1], flags, ei, 2 * NE);
    conv_f_k<<<ceil_div(NN * 128, 256), 256, 0, stream>>>(d_in[0], flags, 0, F2, NN * 128);
    {
        ConvTab T;
        struct { int idx; float* dst; int n; } convs[NCV] = {
            {3, aW_res, 16384}, {4, ab_res, 128}, {5, aWg1, 16384}, {6, aas1, 128},
            {7, aad1, 128}, {9, ag1, 128}, {10, abe1, 128}, {11, aWg2, 16384},
            {12, aas2, 128}, {13, aad2, 128}, {15, ag2, 128}, {16, abe2, 128},
            {17, aWs1, 16384}, {18, abs1, 64}, {19, aWs2, 64}, {20, abs2, 1},
            {21, aWc1, 8192}, {22, abc1, 64}, {23, agc, 64}, {24, abec, 64},
            {25, aWc2, 2560}, {26, abc2, 40},
        };
        for (int i = 0; i < NCV; ++i) {
            T.src[i] = convs[i].idx;
            T.dstOff[i] = (int)(convs[i].dst - wa);
            T.n[i] = convs[i].n;
        }
        conv_all_k<<<NCV, 256, 0, stream>>>(P, T, flags, wa);
    }
    repack_ws1_k<<<ceil_div(16384, 256), 256, 0, stream>>>(aWs1, aWs1f);
    hipMemsetAsync(errflag, 0, 4, stream);
    check_k<<<ceil_div(2 * NE, 256), 256, 0, stream>>>(ei, errflag);

    // ---- CSR builds ----
    hipMemsetAsync(curG, 0, (size_t)NN * 4, stream);
    deg_dst_k<<<ceil_div(NA, 256), 256, 0, stream>>>(ei, curG);
    scan1_k<<<NB, 256, 0, stream>>>(curG, offsG, bsums, NN);
    scan2_k<<<1, 256, 0, stream>>>(bsums, NB);
    scan3_k<<<ceil_div(NN + 1, 256), 256, 0, stream>>>(offsG, bsums, NN, NB);
    copy_k<<<ceil_div(NN, 256), 256, 0, stream>>>(offsG, curG, NN);
    scat_dst_k<<<ceil_div(NA, 256), 256, 0, stream>>>(ei, curG, entG, entD);

    hipMemsetAsync(curR, 0, (size_t)NN * 4, stream);
    deg_row_k<<<ceil_div(NE, 256), 256, 0, stream>>>(ei, curR);
    scan1_k<<<NB, 256, 0, stream>>>(curR, offsR, bsums, NN);
    scan2_k<<<1, 256, 0, stream>>>(bsums, NB);
    scan3_k<<<ceil_div(NN + 1, 256), 256, 0, stream>>>(offsR, bsums, NN, NB);
    copy_k<<<ceil_div(NN, 256), 256, 0, stream>>>(offsR, curR, NN);
    scat_row_k<<<ceil_div(NE, 256), 256, 0, stream>>>(ei, curR, entRc, entRe);

    // ---- 1) x_proj ----
    gemm_k<128, 128, 32, false, 0><<<ceil_div(NN, 32), 256, 0, stream>>>(
        F2, nullptr, nullptr, aW_res, 128, ab_res, F1, NN);

    // ---- GAT layer 1 ----
    gemm_k<128, 128, 32, false, 0><<<ceil_div(NN, 32), 256, 0, stream>>>(
        F1, nullptr, nullptr, aWg1, 128, nullptr, F2, NN);
    hipMemsetAsync(keyM, 0, 16 * 8, stream);
    att_scores_k<<<ceil_div(NN * NH, 256), 256, 0, stream>>>(F2, aas1, aad1, a_src, a_dst, keyM);
    edge_exp_k<<<ceil_div(NA * NH, 256), 256, 0, stream>>>(entG, entD, a_src, a_dst, keyM, expv);
    gat_gather_k<<<ceil_div(NN * 64, 256), 256, 0, stream>>>(offsG, entG, F2, expv, F4);
    hipMemsetAsync(stats, 0, 2 * ND * 8, stream);
    bn_stats1_k<128><<<ceil_div(NN, 256), 256, 0, stream>>>(F4, stats, 256);
    bn_fin_k<128><<<1, 128, 0, stream>>>(stats, ag1, abe1, ss);

    // ---- GAT layer 2 (BN1+ELU fused into X staging) ----
    gemm_k<128, 128, 32, false, 1><<<ceil_div(NN, 32), 256, 0, stream>>>(
        F4, nullptr, ss, aWg2, 128, nullptr, F2, NN);
    hipMemsetAsync(keyM, 0, 16 * 8, stream);
    att_scores_k<<<ceil_div(NN * NH, 256), 256, 0, stream>>>(F2, aas2, aad2, a_src, a_dst, keyM);
    edge_exp_k<<<ceil_div(NA * NH, 256), 256, 0, stream>>>(entG, entD, a_src, a_dst, keyM, expv);
    gat_gather_k<<<ceil_div(NN * 64, 256), 256, 0, stream>>>(offsG, entG, F2, expv, F4);
    hipMemsetAsync(stats, 0, 2 * ND * 8, stream);
    bn_stats1_k<128><<<ceil_div(NN, 256), 256, 0, stream>>>(F4, stats, 256);
    bn_fin_k<128><<<1, 128, 0, stream>>>(stats, ag2, abe2, ss);
    bn_apply_ss_k<128, 0><<<ceil_div(NN * ND, 256), 256, 0, stream>>>(F4, ss, F3);  // h_base

    // ---- fused pr|pc gemm ----
    gemm_k<128, 128, 32, false, 0><<<ceil_div(NN, 32), 256, 0, stream>>>(
        F3, nullptr, nullptr, aWs1f, 128, nullptr, F2, NN);

    // ---- edge logits (row-grouped; pr register-cached) ----
    edge_logits_row_k<<<ceil_div(NN * 64, 256), 256, 0, stream>>>(
        offsR, entRc, entRe, (const float4*)F2, (const float4*)abs1, (const float4*)aWs2,
        abs2, d_in[2], flags, out);

    // ---- agg (ballot-compacted gather) -> F1 ----
    agg_gather_k<<<ceil_div(NN * 64, 256), 256, 0, stream>>>(offsR, entRc, entRe, out + WOFF,
                                                             F3, F1);

    // ---- t = (h_base + agg) @ Wc1.T + bc1 ----
    gemm_k<64, 128, 16, true, 0><<<ceil_div(NN, 64), 256, 0, stream>>>(
        F3, F1, nullptr, aWc1, 128, abc1, F4, NN);

    hipMemsetAsync(stats, 0, 2 * NHID * 8, stream);
    bn_stats1_k<64><<<ceil_div(NN, 256), 256, 0, stream>>>(F4, stats, 256);
    bn_fin_k<64><<<1, 64, 0, stream>>>(stats, agc, abec, ss);

    // ---- logits (BN+ReLU fused into X staging) ----
    float* logits = F4 + (size_t)NN * NHID;
    gemm_k<40, 64, 10, false, 2><<<ceil_div(NN, 100), 256, 0, stream>>>(
        F4, nullptr, ss, aWc2, 64, abc2, logits, NN);

    logsoftmax_k<<<ceil_div(NN * 64, 256), 256, 0, stream>>>(logits, out);

    finalize_k<<<1, 1, 0, stream>>>(errflag, out);
}

// Round 18
// 1034.614 us; speedup vs baseline: 1.0360x; 1.0360x over previous
//
#include <hip/hip_runtime.h>
#include <hip/hip_bf16.h>

#define NN 50000
#define NE 800000
#define NA (NE + NN)
#define NH 8
#define NC 16
#define ND 128
#define NHID 64
#define NSH 64
#define NOUT 40
#define BN_EPS 1e-5

#define WOFF (NN * NOUT)
#define LOFF (WOFF + NE)
#define NIN 27
#define NCV 22

static inline int ceil_div(int a, int b) { return (a + b - 1) / b; }

typedef __hip_bfloat16 bf16;
__device__ inline float b2f(bf16 v) { return __bfloat162float(v); }

struct Ptrs { const void* p[NIN]; int n[NIN]; };
struct ConvTab { int src[NCV]; int dstOff[NCV]; int n[NCV]; };

__global__ void sent_k(float* out, float v) { out[0] = v; }

// ---------- dtype detection (fp32 vs bf16; int32 vs int64) ----------
__global__ __launch_bounds__(64) void detect_k(Ptrs P, int* flags) {
    int b = blockIdx.x, lane = threadIdx.x;
    const void* p = P.p[b];
    int n = P.n[b];
    if (b == 1) {
        const int* w = (const int*)p;
        int m = n < 256 ? n : 256;
        int oddNz = 0;
        for (int i = lane; i < m; i += 64)
            if ((i & 1) && w[i] != 0) oddNz = 1;
        unsigned long long any = __ballot(oddNz);
        if (lane == 0) flags[1] = (any == 0ULL) ? 1 : 0;   // 1 => int64
        return;
    }
    int m = n < 256 ? n : 256;
    const bf16* hb = (const bf16*)p;
    int impl = 0, evenNz = 0, oddNz = 0;
    for (int i = lane; i < m; i += 64) {
        float v = b2f(hb[i]);
        bool bad = !isfinite(v) || fabsf(v) > 64.0f || (v != 0.0f && fabsf(v) < 1e-6f);
        if (bad) impl++;
        if (v != 0.0f) { if (i & 1) oddNz = 1; else evenNz = 1; }
    }
#pragma unroll
    for (int off = 32; off > 0; off >>= 1) impl += __shfl_down(impl, off, 64);
    unsigned long long be = __ballot(evenNz), bo = __ballot(oddNz);
    if (lane == 0) {
        int thresh = (m >= 8) ? (m / 8) : 1;
        int isF32 = 0;
        if (impl >= thresh) isF32 = 1;
        else if (be == 0ULL && bo != 0ULL) isF32 = 1;
        flags[b] = isF32;
    }
}

__global__ __launch_bounds__(256) void conv_f_k(const void* __restrict__ src,
                                                const int* __restrict__ flags, int fi,
                                                float* __restrict__ dst, int n) {
    int i = blockIdx.x * 256 + threadIdx.x;
    if (i >= n) return;
    dst[i] = flags[fi] ? ((const float*)src)[i] : b2f(((const bf16*)src)[i]);
}

__global__ __launch_bounds__(256) void conv_all_k(Ptrs P, ConvTab T,
                                                  const int* __restrict__ flags,
                                                  float* __restrict__ wa) {
    int b = blockIdx.x;
    const void* src = P.p[T.src[b]];
    int isf = flags[T.src[b]];
    float* dst = wa + T.dstOff[b];
    int n = T.n[b];
    for (int i = threadIdx.x; i < n; i += 256)
        dst[i] = isf ? ((const float*)src)[i] : b2f(((const bf16*)src)[i]);
}

// repack Ws1 [64][256] -> fused [128][128]
__global__ __launch_bounds__(256) void repack_ws1_k(const float* __restrict__ s,
                                                    float* __restrict__ d) {
    int id = blockIdx.x * 256 + threadIdx.x;
    if (id >= 128 * 128) return;
    int m = id >> 7, k = id & 127;
    d[id] = (m < 64) ? s[m * 256 + k] : s[(m - 64) * 256 + 128 + k];
}

__global__ __launch_bounds__(256) void conv_i_k(const void* __restrict__ src,
                                                const int* __restrict__ flags,
                                                int* __restrict__ dst, int n) {
    int i = blockIdx.x * 256 + threadIdx.x;
    if (i >= n) return;
    const int* s = (const int*)src;
    dst[i] = flags[1] ? s[2 * i] : s[i];
}

__global__ __launch_bounds__(256) void check_k(const int* __restrict__ ei, int* err) {
    int i = blockIdx.x * 256 + threadIdx.x;
    if (i < 2 * NE && (unsigned)ei[i] >= NN) atomicOr(err, 1);
}
__global__ void finalize_k(const int* err, float* out) {
    if (*err) out[0] = 800.0f;
}

// ---------- ordered-key mapping for fp64 atomic max ----------
__device__ inline unsigned long long d2key(double v) {
    unsigned long long b = __double_as_longlong(v);
    return (b & 0x8000000000000000ULL) ? ~b : (b | 0x8000000000000000ULL);
}
__device__ inline double key2d(unsigned long long k) {
    return (k & 0x8000000000000000ULL) ? __longlong_as_double(k & 0x7fffffffffffffffULL)
                                       : __longlong_as_double(~k);
}

// ---------- CSR build ----------
__global__ __launch_bounds__(256) void deg_dst_k(const int* __restrict__ ei, int* deg) {
    int e = blockIdx.x * 256 + threadIdx.x;
    if (e >= NA) return;
    int d = (e < NE) ? ei[NE + e] : e - NE;
    if ((unsigned)d < NN) atomicAdd(&deg[d], 1);
}
__global__ __launch_bounds__(256) void deg_row_k(const int* __restrict__ ei, int* deg) {
    int e = blockIdx.x * 256 + threadIdx.x;
    if (e >= NE) return;
    int r = ei[e];
    if ((unsigned)r < NN) atomicAdd(&deg[r], 1);
}

__global__ __launch_bounds__(256) void scan1_k(const int* __restrict__ deg,
                                               int* __restrict__ offs,
                                               int* __restrict__ bsums, int n) {
    __shared__ int sh[256];
    int i = blockIdx.x * 256 + threadIdx.x;
    int v = (i < n) ? deg[i] : 0;
    sh[threadIdx.x] = v;
    __syncthreads();
    int acc = v;
    for (int off = 1; off < 256; off <<= 1) {
        int t = (threadIdx.x >= off) ? sh[threadIdx.x - off] : 0;
        __syncthreads();
        acc += t;
        sh[threadIdx.x] = acc;
        __syncthreads();
    }
    if (i < n) offs[i] = acc - v;
    if (threadIdx.x == 255) bsums[blockIdx.x] = acc;
}
__global__ __launch_bounds__(256) void scan2_k(int* __restrict__ bsums, int nb) {
    __shared__ int sh[256];
    int t = threadIdx.x;
    int v = (t < nb) ? bsums[t] : 0;
    sh[t] = v;
    __syncthreads();
    int acc = v;
    for (int off = 1; off < 256; off <<= 1) {
        int x = (t >= off) ? sh[t - off] : 0;
        __syncthreads();
        acc += x;
        sh[t] = acc;
        __syncthreads();
    }
    if (t < nb) bsums[t] = acc - v;
    if (t == nb - 1) bsums[nb] = acc;
}
__global__ __launch_bounds__(256) void scan3_k(int* __restrict__ offs,
                                               const int* __restrict__ bsums, int n, int nb) {
    int i = blockIdx.x * 256 + threadIdx.x;
    if (i < n) offs[i] += bsums[blockIdx.x];
    else if (i == n) offs[n] = bsums[nb];
}
__global__ __launch_bounds__(256) void copy_k(const int* __restrict__ a, int* __restrict__ b,
                                              int n) {
    int i = blockIdx.x * 256 + threadIdx.x;
    if (i < n) b[i] = a[i];
}

__global__ __launch_bounds__(256) void scat_dst_k(const int* __restrict__ ei, int* cur,
                                                  int* __restrict__ entS,
                                                  int* __restrict__ entD) {
    int e = blockIdx.x * 256 + threadIdx.x;
    if (e >= NA) return;
    int s, d;
    if (e < NE) { s = ei[e]; d = ei[NE + e]; }
    else        { s = d = e - NE; }
    if ((unsigned)s >= NN || (unsigned)d >= NN) return;
    int pos = atomicAdd(&cur[d], 1);
    entS[pos] = s;
    entD[pos] = d;
}
__global__ __launch_bounds__(256) void scat_row_k(const int* __restrict__ ei, int* cur,
                                                  int* __restrict__ entc,
                                                  int* __restrict__ ente) {
    int e = blockIdx.x * 256 + threadIdx.x;
    if (e >= NE) return;
    int r = ei[e], c = ei[NE + e];
    if ((unsigned)r >= NN || (unsigned)c >= NN) return;
    int pos = atomicAdd(&cur[r], 1);
    entc[pos] = c;
    ente[pos] = e;
}

// ---------- tiled GEMM: hybrid accumulation; optional fused attention-score epilogue ----------
// Compute/store guarded by t < TR*TC (TC=10 has 6 inactive threads!).
// ATT requires TC==32 (all threads active) — enforced by static_assert.
template <int M, int K, int TC, bool ADD2, int XBN, bool ATT>
__global__ __launch_bounds__(256) void gemm_k(const float* __restrict__ X,
                                              const float* __restrict__ X2,
                                              const float2* __restrict__ ssX,
                                              const float* __restrict__ W, int wstride,
                                              const float* __restrict__ bias,
                                              float* __restrict__ Y, int nrows,
                                              const float* __restrict__ asw,
                                              const float* __restrict__ adw,
                                              double* __restrict__ a_src,
                                              double* __restrict__ a_dst,
                                              unsigned long long* __restrict__ keyM) {
    static_assert(!ATT || TC == 32, "ATT epilogue requires TC==32");
    constexpr int KT = 32;
    constexpr int TR = 256 / TC;
    constexpr int ROWS = TR * 4;
    __shared__ float Ws[KT][M + 4];
    __shared__ float Xs[ROWS][KT + 4];
    __shared__ double redS[ATT ? NH : 1][8], redD[ATT ? NH : 1][8];

    const int t = threadIdx.x;
    const int lane = t & 63, wv = t >> 6;
    const int row0 = blockIdx.x * ROWS;

    double acc[4][4];
#pragma unroll
    for (int i = 0; i < 4; ++i)
#pragma unroll
        for (int j = 0; j < 4; ++j) acc[i][j] = 0.0;

    for (int k0 = 0; k0 < K; k0 += KT) {
        {
            const int mi = lane >> 3, ki = lane & 7;
            for (int b = wv; b < (M / 8) * (KT / 8); b += 4) {
                int bm = b % (M / 8), bk = b / (M / 8);
                int m = bm * 8 + mi, kk = bk * 8 + ki;
                Ws[kk][m] = W[(size_t)m * wstride + k0 + kk];
            }
        }
        for (int idx = t; idx < ROWS * KT; idx += 256) {
            int r = idx / KT, kk = idx % KT;
            int row = row0 + r;
            float v = 0.0f;
            if (row < nrows) {
                v = X[(size_t)row * K + k0 + kk];
                if (ADD2) v += X2[(size_t)row * K + k0 + kk];
                if (XBN) {
                    float2 s = ssX[k0 + kk];
                    v = v * s.x + s.y;
                    if (XBN == 1) v = v > 0.0f ? v : expm1f(v);
                    else          v = v > 0.0f ? v : 0.0f;
                }
            }
            Xs[r][kk] = v;
        }
        __syncthreads();

        if (t < TR * TC) {
            const int c0 = (t % TC) * 4;
            const int r0 = (t / TC) * 4;
            float facc[4][4];
#pragma unroll
            for (int i = 0; i < 4; ++i)
#pragma unroll
                for (int j = 0; j < 4; ++j) facc[i][j] = 0.0f;
#pragma unroll 4
            for (int kk = 0; kk < KT; ++kk) {
                float4 w = *(const float4*)&Ws[kk][c0];
#pragma unroll
                for (int i = 0; i < 4; ++i) {
                    float x = Xs[r0 + i][kk];
                    facc[i][0] += x * w.x;
                    facc[i][1] += x * w.y;
                    facc[i][2] += x * w.z;
                    facc[i][3] += x * w.w;
                }
                if ((kk & 15) == 15) {
#pragma unroll
                    for (int i = 0; i < 4; ++i)
#pragma unroll
                        for (int j = 0; j < 4; ++j) {
                            acc[i][j] += (double)facc[i][j];
                            facc[i][j] = 0.0f;
                        }
                }
            }
        }
        __syncthreads();
    }

    float yv[4][4];
    if (t < TR * TC) {
        const int c0 = (t % TC) * 4;
        const int r0 = (t / TC) * 4;
#pragma unroll
        for (int i = 0; i < 4; ++i) {
            int row = row0 + r0 + i;
#pragma unroll
            for (int j = 0; j < 4; ++j) {
                double v = acc[i][j];
                if (bias) v += (double)bias[c0 + j];
                yv[i][j] = (float)v;
                if (row < nrows) Y[(size_t)row * M + c0 + j] = yv[i][j];
            }
        }
    }

    if constexpr (ATT) {   // TC==32: all 256 threads active, yv valid everywhere
        const int c0 = (t % TC) * 4;
        const int r0 = (t / TC) * 4;
        double ps[4], pd[4];
#pragma unroll
        for (int i = 0; i < 4; ++i) {
            double s = 0.0, d = 0.0;
#pragma unroll
            for (int j = 0; j < 4; ++j) {
                double vv = (double)yv[i][j];
                s += vv * (double)asw[c0 + j];
                d += vv * (double)adw[c0 + j];
            }
            ps[i] = s; pd[i] = d;
        }
#pragma unroll
        for (int off = 1; off <= 2; off <<= 1) {
#pragma unroll
            for (int i = 0; i < 4; ++i) {
                ps[i] += __shfl_xor(ps[i], off, 64);
                pd[i] += __shfl_xor(pd[i], off, 64);
            }
        }
        const int head = (t % TC) >> 2;
        const int rg = t >> 5;
        if ((lane & 3) == 0) {
            double mS = -1e300, mD = -1e300;
#pragma unroll
            for (int i = 0; i < 4; ++i) {
                int row = row0 + r0 + i;
                if (row < nrows) {
                    a_src[(size_t)row * NH + head] = ps[i];
                    a_dst[(size_t)row * NH + head] = pd[i];
                    if (ps[i] > mS) mS = ps[i];
                    if (pd[i] > mD) mD = pd[i];
                }
            }
            redS[head][rg] = mS;
            redD[head][rg] = mD;
        }
        __syncthreads();
        if (t < NH) {
            double mS = -1e300, mD = -1e300;
#pragma unroll
            for (int g = 0; g < 8; ++g) {
                if (redS[t][g] > mS) mS = redS[t][g];
                if (redD[t][g] > mD) mD = redD[t][g];
            }
            atomicMax(&keyM[t], d2key(mS));
            atomicMax(&keyM[NH + t], d2key(mD));
        }
    }
}

// ---------- edge-parallel exp (fp32 expf; x computed fp64) ----------
__global__ __launch_bounds__(256) void edge_exp_k(const int* __restrict__ entS,
                                                  const int* __restrict__ entD,
                                                  const double* __restrict__ a_src,
                                                  const double* __restrict__ a_dst,
                                                  const unsigned long long* __restrict__ keyM,
                                                  float* __restrict__ expv) {
    int id = blockIdx.x * 256 + threadIdx.x;
    if (id >= NA * NH) return;
    int i = id >> 3, hh = id & 7;
    int s = entS[i], d = entD[i];
    double x = a_src[(size_t)s * NH + hh] + a_dst[(size_t)d * NH + hh];
    x = x > 0.0 ? x : 0.2 * x;
    double M = key2d(keyM[hh]) + key2d(keyM[NH + hh]);
    if (M < 0.0) M = 0.0;
    expv[id] = expf((float)(x - M));
}

// ---------- GAT gather: wave per dst, float2 feature packing, unroll-4 ----------
__global__ __launch_bounds__(256) void gat_gather_k(const int* __restrict__ offs,
                                                    const int* __restrict__ ent,
                                                    const float* __restrict__ h,
                                                    const float* __restrict__ expv,
                                                    float* __restrict__ outb) {
    int wv = (blockIdx.x * 256 + threadIdx.x) >> 6;
    int lane = threadIdx.x & 63;
    if (wv >= NN) return;
    const int s0 = offs[wv], s1 = offs[wv + 1];
    const int hh = lane >> 3;
    double acc0 = 0.0, acc1 = 0.0, den = 0.0;
    int i = s0;
    for (; i + 4 <= s1; i += 4) {
        int sA = ent[i], sB = ent[i + 1], sC = ent[i + 2], sD = ent[i + 3];
        float eA = expv[(size_t)(i + 0) * NH + hh];
        float eB = expv[(size_t)(i + 1) * NH + hh];
        float eC = expv[(size_t)(i + 2) * NH + hh];
        float eD = expv[(size_t)(i + 3) * NH + hh];
        float2 a = *(const float2*)&h[(size_t)sA * ND + 2 * lane];
        float2 b = *(const float2*)&h[(size_t)sB * ND + 2 * lane];
        float2 c = *(const float2*)&h[(size_t)sC * ND + 2 * lane];
        float2 d = *(const float2*)&h[(size_t)sD * ND + 2 * lane];
        acc0 += (double)a.x * eA; acc1 += (double)a.y * eA; den += (double)eA;
        acc0 += (double)b.x * eB; acc1 += (double)b.y * eB; den += (double)eB;
        acc0 += (double)c.x * eC; acc1 += (double)c.y * eC; den += (double)eC;
        acc0 += (double)d.x * eD; acc1 += (double)d.y * eD; den += (double)eD;
    }
    for (; i < s1; ++i) {
        int s = ent[i];
        float e = expv[(size_t)i * NH + hh];
        float2 a = *(const float2*)&h[(size_t)s * ND + 2 * lane];
        acc0 += (double)a.x * e; acc1 += (double)a.y * e; den += (double)e;
    }
    double inv = den > 0.0 ? 1.0 / den : 0.0;
    float2 o = make_float2((float)(acc0 * inv), (float)(acc1 * inv));
    *(float2*)&outb[(size_t)wv * ND + 2 * lane] = o;
}

// ---------- one-pass BN stats ----------
template <int M>
__global__ __launch_bounds__(256) void bn_stats1_k(const float* __restrict__ X,
                                                   double* __restrict__ stats, int rpb) {
    constexpr int G = 256 / M;
    __shared__ double sh0[256], sh1[256];
    int f = threadIdx.x % M, g = threadIdx.x / M;
    int r0 = blockIdx.x * rpb;
    int rend = r0 + rpb; if (rend > NN) rend = NN;
    double s = 0.0, s2 = 0.0;
    for (int r = r0 + g; r < rend; r += G) {
        double v = (double)X[(size_t)r * M + f];
        s += v;
        s2 += v * v;
    }
    sh0[threadIdx.x] = s;
    sh1[threadIdx.x] = s2;
    __syncthreads();
    if (g == 0) {
#pragma unroll
        for (int gg = 1; gg < G; ++gg) { s += sh0[gg * M + f]; s2 += sh1[gg * M + f]; }
        atomicAdd(&stats[f], s);
        atomicAdd(&stats[M + f], s2);
    }
}

template <int M>
__global__ void bn_fin_k(const double* __restrict__ stats,
                         const float* __restrict__ gamma, const float* __restrict__ beta,
                         float2* __restrict__ ss) {
    int f = threadIdx.x;
    if (f >= M) return;
    double mu = stats[f] / (double)NN;
    double var = stats[M + f] / (double)NN - mu * mu;
    if (var < 0.0) var = 0.0;
    double sc = (double)gamma[f] / sqrt(var + BN_EPS);
    ss[f] = make_float2((float)sc, (float)((double)beta[f] - mu * sc));
}

template <int M, int ACT>
__global__ __launch_bounds__(256) void bn_apply_ss_k(const float* __restrict__ X,
                                                     const float2* __restrict__ ss,
                                                     float* __restrict__ Y) {
    int id = blockIdx.x * 256 + threadIdx.x;
    if (id >= NN * M) return;
    float2 s = ss[id % M];
    float v = X[id] * s.x + s.y;
    if (ACT == 0) v = v > 0.0f ? v : expm1f(v);
    else          v = v > 0.0f ? v : 0.0f;
    Y[id] = v;
}

// ---------- edge logits: FLAT, 16 lanes/edge, fused pr|pc buffer (coalesced writes) ----------
__global__ __launch_bounds__(256) void edge_logits_k(const int* __restrict__ ei,
                                                     const float4* __restrict__ fused4,
                                                     const float4* __restrict__ bs14,
                                                     const float4* __restrict__ Ws24,
                                                     const float* __restrict__ bs2,
                                                     const void* __restrict__ graw,
                                                     const int* __restrict__ flags,
                                                     float* __restrict__ out) {
    int tid = blockIdx.x * 256 + threadIdx.x;
    int e = tid >> 4;
    int g = tid & 15;
    if (e >= NE) return;
    int r = ei[e], c = ei[NE + e];
    if ((unsigned)r >= NN || (unsigned)c >= NN) return;
    float4 a = fused4[(size_t)r * 32 + g];
    float4 b = fused4[(size_t)c * 32 + 16 + g];
    float4 s1 = bs14[g];
    float4 w2 = Ws24[g];
    double v = 0.0;
    double t0 = (double)a.x + (double)b.x + (double)s1.x; t0 = t0 > 0.0 ? t0 : 0.0;
    double t1 = (double)a.y + (double)b.y + (double)s1.y; t1 = t1 > 0.0 ? t1 : 0.0;
    double t2 = (double)a.z + (double)b.z + (double)s1.z; t2 = t2 > 0.0 ? t2 : 0.0;
    double t3 = (double)a.w + (double)b.w + (double)s1.w; t3 = t3 > 0.0 ? t3 : 0.0;
    v = t0 * (double)w2.x + t1 * (double)w2.y + t2 * (double)w2.z + t3 * (double)w2.w;
#pragma unroll
    for (int off = 8; off > 0; off >>= 1) v += __shfl_xor(v, off, 64);
    if (g == 0) {
        double L = v + (double)bs2[0];
        double g0, g1;
        if (flags[2]) {
            const float* gp = (const float*)graw;
            g0 = (double)gp[2 * e]; g1 = (double)gp[2 * e + 1];
        } else {
            const bf16* gp = (const bf16*)graw;
            g0 = (double)b2f(gp[2 * e]); g1 = (double)b2f(gp[2 * e + 1]);
        }
        out[WOFF + e] = ((L + g1) > g0) ? 1.0f : 0.0f;
        out[LOFF + e] = (float)L;
    }
}

// ---------- sparse agg gather: ballot-compaction + float2 packing + unroll-4 ----------
__global__ __launch_bounds__(256) void agg_gather_k(const int* __restrict__ offs,
                                                    const int* __restrict__ entc,
                                                    const int* __restrict__ ente,
                                                    const float* __restrict__ w,
                                                    const float* __restrict__ hb,
                                                    float* __restrict__ aggF) {
    __shared__ int selBuf[4][64];
    int wv = (blockIdx.x * 256 + threadIdx.x) >> 6;
    int lane = threadIdx.x & 63;
    int wloc = (threadIdx.x >> 6);
    if (wv >= NN) return;
    int* sel = selBuf[wloc];
    const int s0 = offs[wv], s1 = offs[wv + 1];
    double a0 = 0.0, a1 = 0.0;
    for (int base = s0; base < s1; base += 64) {
        int i = base + lane;
        int c = 0;
        bool keep = false;
        if (i < s1) {
            c = entc[i];
            keep = w[ente[i]] > 0.5f;
        }
        unsigned long long m = __ballot(keep);
        int cnt = __popcll(m);
        if (keep) {
            int pos = __popcll(m & ((1ULL << lane) - 1ULL));
            sel[pos] = c;
        }
        __builtin_amdgcn_wave_barrier();
        int j = 0;
        for (; j + 4 <= cnt; j += 4) {
            int cA = sel[j], cB = sel[j + 1], cC = sel[j + 2], cD = sel[j + 3];
            float2 hA = *(const float2*)&hb[(size_t)cA * ND + 2 * lane];
            float2 hB = *(const float2*)&hb[(size_t)cB * ND + 2 * lane];
            float2 hC = *(const float2*)&hb[(size_t)cC * ND + 2 * lane];
            float2 hD = *(const float2*)&hb[(size_t)cD * ND + 2 * lane];
            a0 += (double)hA.x; a1 += (double)hA.y;
            a0 += (double)hB.x; a1 += (double)hB.y;
            a0 += (double)hC.x; a1 += (double)hC.y;
            a0 += (double)hD.x; a1 += (double)hD.y;
        }
        for (; j < cnt; ++j) {
            int c2 = sel[j];
            float2 hv = *(const float2*)&hb[(size_t)c2 * ND + 2 * lane];
            a0 += (double)hv.x; a1 += (double)hv.y;
        }
        __builtin_amdgcn_wave_barrier();
    }
    float2 o = make_float2((float)a0, (float)a1);
    *(float2*)&aggF[(size_t)wv * ND + 2 * lane] = o;
}

// ---------- log-softmax (fp32) ----------
__global__ __launch_bounds__(256) void logsoftmax_k(const float* __restrict__ Y,
                                                    float* __restrict__ out) {
    int wid = (blockIdx.x * 256 + threadIdx.x) / 64;
    int lane = threadIdx.x & 63;
    if (wid >= NN) return;
    float v = (lane < NOUT) ? Y[(size_t)wid * NOUT + lane] : -1e30f;
    float m = v;
#pragma unroll
    for (int off = 32; off > 0; off >>= 1) {
        float o = __shfl_xor(m, off, 64);
        m = m > o ? m : o;
    }
    float ex = (lane < NOUT) ? expf(v - m) : 0.0f;
    float s = ex;
#pragma unroll
    for (int off = 32; off > 0; off >>= 1) s += __shfl_xor(s, off, 64);
    if (lane < NOUT) out[(size_t)wid * NOUT + lane] = v - m - logf(s);
}

extern "C" void kernel_launch(void* const* d_in, const int* in_sizes, int n_in,
                              void* d_out, int out_size, void* d_ws, size_t ws_size,
                              hipStream_t stream) {
    float* out = (float*)d_out;

    static const int EXPS[NIN] = {
        NN * 128, 2 * NE, 2 * NE, 16384, 128, 16384, 128, 128, 128, 128, 128,
        16384, 128, 128, 128, 128, 128, 16384, 64, 64, 1, 8192, 64, 64, 64, 2560, 40 };
    if (n_in != NIN) { sent_k<<<1, 1, 0, stream>>>(out, 700.0f); return; }
    if (out_size != NN * NOUT + 2 * NE) { sent_k<<<1, 1, 0, stream>>>(out, 600.0f); return; }
    for (int i = 0; i < NIN; ++i)
        if (in_sizes[i] != EXPS[i]) {
            sent_k<<<1, 1, 0, stream>>>(out, 1000.0f + 128.0f * i);
            return;
        }

    // ---- workspace layout ----
    char* W = (char*)d_ws;
    double* a_src = (double*)W;                      W += (size_t)NN * NH * 8;
    double* a_dst = (double*)W;                      W += (size_t)NN * NH * 8;
    double* stats = (double*)W;                      W += 256 * 8;
    unsigned long long* keyM = (unsigned long long*)W; W += 16 * 8;
    float2* ss = (float2*)W;                         W += 128 * 8;
    float* F1 = (float*)W;                           W += (size_t)NN * ND * 4;
    float* F2 = (float*)W;                           W += (size_t)NN * ND * 4;
    float* F3 = (float*)W;                           W += (size_t)NN * ND * 4;
    float* F4 = (float*)W;                           W += (size_t)NN * ND * 4;
    float* expv = (float*)W;                         W += (size_t)NA * NH * 4;
    float* wa = (float*)W;
    int off = 0;
    float* aW_res = wa + off; off += 16384;
    float* ab_res = wa + off; off += 128;
    float* aWg1 = wa + off; off += 16384;
    float* aas1 = wa + off; off += 128;
    float* aad1 = wa + off; off += 128;
    float* ag1  = wa + off; off += 128;
    float* abe1 = wa + off; off += 128;
    float* aWg2 = wa + off; off += 16384;
    float* aas2 = wa + off; off += 128;
    float* aad2 = wa + off; off += 128;
    float* ag2  = wa + off; off += 128;
    float* abe2 = wa + off; off += 128;
    float* aWs1 = wa + off; off += 16384;
    float* abs1 = wa + off; off += 64;
    float* aWs2 = wa + off; off += 64;
    float* abs2 = wa + off; off += 4;
    float* aWc1 = wa + off; off += 8192;
    float* abc1 = wa + off; off += 64;
    float* agc  = wa + off; off += 64;
    float* abec = wa + off; off += 64;
    float* aWc2 = wa + off; off += 2560;
    float* abc2 = wa + off; off += 40;
    float* aWs1f = wa + off; off += 16384;
    W = (char*)(wa + off);
    int* ei    = (int*)W;  W += (size_t)2 * NE * 4;
    int* offsG = (int*)W;  W += (size_t)(NN + 1) * 4;
    int* curG  = (int*)W;  W += (size_t)NN * 4;
    int* entG  = (int*)W;  W += (size_t)NA * 4;
    int* entD  = (int*)W;  W += (size_t)NA * 4;
    int* offsR = (int*)W;  W += (size_t)(NN + 1) * 4;
    int* curR  = (int*)W;  W += (size_t)NN * 4;
    int* entRc = (int*)W;  W += (size_t)NE * 4;
    int* entRe = (int*)W;  W += (size_t)NE * 4;
    int* bsums = (int*)W;  W += 260 * 4;
    int* flags = (int*)W;  W += 32 * 4;
    int* errflag = (int*)W; W += 4;
    if ((size_t)(W - (char*)d_ws) > ws_size) { sent_k<<<1, 1, 0, stream>>>(out, 900.0f); return; }

    const int NB = ceil_div(NN, 256);

    // ---- 0) detect & convert ----
    Ptrs P;
    for (int i = 0; i < NIN; ++i) { P.p[i] = d_in[i]; P.n[i] = in_sizes[i]; }
    detect_k<<<NIN, 64, 0, stream>>>(P, flags);
    conv_i_k<<<ceil_div(2 * NE, 256), 256, 0, stream>>>(d_in[1], flags, ei, 2 * NE);
    conv_f_k<<<ceil_div(NN * 128, 256), 256, 0, stream>>>(d_in[0], flags, 0, F2, NN * 128);
    {
        ConvTab T;
        struct { int idx; float* dst; int n; } convs[NCV] = {
            {3, aW_res, 16384}, {4, ab_res, 128}, {5, aWg1, 16384}, {6, aas1, 128},
            {7, aad1, 128}, {9, ag1, 128}, {10, abe1, 128}, {11, aWg2, 16384},
            {12, aas2, 128}, {13, aad2, 128}, {15, ag2, 128}, {16, abe2, 128},
            {17, aWs1, 16384}, {18, abs1, 64}, {19, aWs2, 64}, {20, abs2, 1},
            {21, aWc1, 8192}, {22, abc1, 64}, {23, agc, 64}, {24, abec, 64},
            {25, aWc2, 2560}, {26, abc2, 40},
        };
        for (int i = 0; i < NCV; ++i) {
            T.src[i] = convs[i].idx;
            T.dstOff[i] = (int)(convs[i].dst - wa);
            T.n[i] = convs[i].n;
        }
        conv_all_k<<<NCV, 256, 0, stream>>>(P, T, flags, wa);
    }
    repack_ws1_k<<<ceil_div(16384, 256), 256, 0, stream>>>(aWs1, aWs1f);
    hipMemsetAsync(errflag, 0, 4, stream);
    check_k<<<ceil_div(2 * NE, 256), 256, 0, stream>>>(ei, errflag);

    // ---- CSR builds ----
    hipMemsetAsync(curG, 0, (size_t)NN * 4, stream);
    deg_dst_k<<<ceil_div(NA, 256), 256, 0, stream>>>(ei, curG);
    scan1_k<<<NB, 256, 0, stream>>>(curG, offsG, bsums, NN);
    scan2_k<<<1, 256, 0, stream>>>(bsums, NB);
    scan3_k<<<ceil_div(NN + 1, 256), 256, 0, stream>>>(offsG, bsums, NN, NB);
    copy_k<<<ceil_div(NN, 256), 256, 0, stream>>>(offsG, curG, NN);
    scat_dst_k<<<ceil_div(NA, 256), 256, 0, stream>>>(ei, curG, entG, entD);

    hipMemsetAsync(curR, 0, (size_t)NN * 4, stream);
    deg_row_k<<<ceil_div(NE, 256), 256, 0, stream>>>(ei, curR);
    scan1_k<<<NB, 256, 0, stream>>>(curR, offsR, bsums, NN);
    scan2_k<<<1, 256, 0, stream>>>(bsums, NB);
    scan3_k<<<ceil_div(NN + 1, 256), 256, 0, stream>>>(offsR, bsums, NN, NB);
    copy_k<<<ceil_div(NN, 256), 256, 0, stream>>>(offsR, curR, NN);
    scat_row_k<<<ceil_div(NE, 256), 256, 0, stream>>>(ei, curR, entRc, entRe);

    // ---- 1) x_proj ----
    gemm_k<128, 128, 32, false, 0, false><<<ceil_div(NN, 32), 256, 0, stream>>>(
        F2, nullptr, nullptr, aW_res, 128, ab_res, F1, NN,
        nullptr, nullptr, nullptr, nullptr, nullptr);

    // ---- GAT layer 1 (att scores fused into GEMM epilogue) ----
    hipMemsetAsync(keyM, 0, 16 * 8, stream);
    gemm_k<128, 128, 32, false, 0, true><<<ceil_div(NN, 32), 256, 0, stream>>>(
        F1, nullptr, nullptr, aWg1, 128, nullptr, F2, NN,
        aas1, aad1, a_src, a_dst, keyM);
    edge_exp_k<<<ceil_div(NA * NH, 256), 256, 0, stream>>>(entG, entD, a_src, a_dst, keyM, expv);
    gat_gather_k<<<ceil_div(NN * 64, 256), 256, 0, stream>>>(offsG, entG, F2, expv, F4);
    hipMemsetAsync(stats, 0, 2 * ND * 8, stream);
    bn_stats1_k<128><<<ceil_div(NN, 256), 256, 0, stream>>>(F4, stats, 256);
    bn_fin_k<128><<<1, 128, 0, stream>>>(stats, ag1, abe1, ss);

    // ---- GAT layer 2 (BN1+ELU fused into X staging; att fused in epilogue) ----
    hipMemsetAsync(keyM, 0, 16 * 8, stream);
    gemm_k<128, 128, 32, false, 1, true><<<ceil_div(NN, 32), 256, 0, stream>>>(
        F4, nullptr, ss, aWg2, 128, nullptr, F2, NN,
        aas2, aad2, a_src, a_dst, keyM);
    edge_exp_k<<<ceil_div(NA * NH, 256), 256, 0, stream>>>(entG, entD, a_src, a_dst, keyM, expv);
    gat_gather_k<<<ceil_div(NN * 64, 256), 256, 0, stream>>>(offsG, entG, F2, expv, F4);
    hipMemsetAsync(stats, 0, 2 * ND * 8, stream);
    bn_stats1_k<128><<<ceil_div(NN, 256), 256, 0, stream>>>(F4, stats, 256);
    bn_fin_k<128><<<1, 128, 0, stream>>>(stats, ag2, abe2, ss);
    bn_apply_ss_k<128, 0><<<ceil_div(NN * ND, 256), 256, 0, stream>>>(F4, ss, F3);  // h_base

    // ---- fused pr|pc gemm ----
    gemm_k<128, 128, 32, false, 0, false><<<ceil_div(NN, 32), 256, 0, stream>>>(
        F3, nullptr, nullptr, aWs1f, 128, nullptr, F2, NN,
        nullptr, nullptr, nullptr, nullptr, nullptr);

    // ---- edge logits (flat: coalesced writes) ----
    edge_logits_k<<<ceil_div(NE * 16, 256), 256, 0, stream>>>(
        ei, (const float4*)F2, (const float4*)abs1, (const float4*)aWs2, abs2, d_in[2], flags,
        out);

    // ---- agg (ballot-compacted gather) -> F1 ----
    agg_gather_k<<<ceil_div(NN * 64, 256), 256, 0, stream>>>(offsR, entRc, entRe, out + WOFF,
                                                             F3, F1);

    // ---- t = (h_base + agg) @ Wc1.T + bc1 ----
    gemm_k<64, 128, 16, true, 0, false><<<ceil_div(NN, 64), 256, 0, stream>>>(
        F3, F1, nullptr, aWc1, 128, abc1, F4, NN,
        nullptr, nullptr, nullptr, nullptr, nullptr);

    hipMemsetAsync(stats, 0, 2 * NHID * 8, stream);
    bn_stats1_k<64><<<ceil_div(NN, 256), 256, 0, stream>>>(F4, stats, 256);
    bn_fin_k<64><<<1, 64, 0, stream>>>(stats, agc, abec, ss);

    // ---- logits (BN+ReLU fused into X staging) ----
    float* logits = F4 + (size_t)NN * NHID;
    gemm_k<40, 64, 10, false, 2, false><<<ceil_div(NN, 100), 256, 0, stream>>>(
        F4, nullptr, ss, aWc2, 64, abc2, logits, NN,
        nullptr, nullptr, nullptr, nullptr, nullptr);

    logsoftmax_k<<<ceil_div(NN * 64, 256), 256, 0, stream>>>(logits, out);

    finalize_k<<<1, 1, 0, stream>>>(errflag, out);
}

// Round 19
// 1023.476 us; speedup vs baseline: 1.0473x; 1.0109x over previous
//
#include <hip/hip_runtime.h>
#include <hip/hip_bf16.h>

#define NN 50000
#define NE 800000
#define NA (NE + NN)
#define NH 8
#define NC 16
#define ND 128
#define NHID 64
#define NSH 64
#define NOUT 40
#define BN_EPS 1e-5

#define WOFF (NN * NOUT)
#define LOFF (WOFF + NE)
#define NIN 27
#define NCV 22

static inline int ceil_div(int a, int b) { return (a + b - 1) / b; }

typedef __hip_bfloat16 bf16;
__device__ inline float b2f(bf16 v) { return __bfloat162float(v); }

struct Ptrs { const void* p[NIN]; int n[NIN]; };
struct ConvTab { int src[NCV]; int dstOff[NCV]; int n[NCV]; };

__global__ void sent_k(float* out, float v) { out[0] = v; }

// ---------- dtype detection (fp32 vs bf16; int32 vs int64) ----------
__global__ __launch_bounds__(64) void detect_k(Ptrs P, int* flags) {
    int b = blockIdx.x, lane = threadIdx.x;
    const void* p = P.p[b];
    int n = P.n[b];
    if (b == 1) {
        const int* w = (const int*)p;
        int m = n < 256 ? n : 256;
        int oddNz = 0;
        for (int i = lane; i < m; i += 64)
            if ((i & 1) && w[i] != 0) oddNz = 1;
        unsigned long long any = __ballot(oddNz);
        if (lane == 0) flags[1] = (any == 0ULL) ? 1 : 0;   // 1 => int64
        return;
    }
    int m = n < 256 ? n : 256;
    const bf16* hb = (const bf16*)p;
    int impl = 0, evenNz = 0, oddNz = 0;
    for (int i = lane; i < m; i += 64) {
        float v = b2f(hb[i]);
        bool bad = !isfinite(v) || fabsf(v) > 64.0f || (v != 0.0f && fabsf(v) < 1e-6f);
        if (bad) impl++;
        if (v != 0.0f) { if (i & 1) oddNz = 1; else evenNz = 1; }
    }
#pragma unroll
    for (int off = 32; off > 0; off >>= 1) impl += __shfl_down(impl, off, 64);
    unsigned long long be = __ballot(evenNz), bo = __ballot(oddNz);
    if (lane == 0) {
        int thresh = (m >= 8) ? (m / 8) : 1;
        int isF32 = 0;
        if (impl >= thresh) isF32 = 1;
        else if (be == 0ULL && bo != 0ULL) isF32 = 1;
        flags[b] = isF32;
    }
}

__global__ __launch_bounds__(256) void conv_f_k(const void* __restrict__ src,
                                                const int* __restrict__ flags, int fi,
                                                float* __restrict__ dst, int n) {
    int i = blockIdx.x * 256 + threadIdx.x;
    if (i >= n) return;
    dst[i] = flags[fi] ? ((const float*)src)[i] : b2f(((const bf16*)src)[i]);
}

__global__ __launch_bounds__(256) void conv_all_k(Ptrs P, ConvTab T,
                                                  const int* __restrict__ flags,
                                                  float* __restrict__ wa) {
    int b = blockIdx.x;
    const void* src = P.p[T.src[b]];
    int isf = flags[T.src[b]];
    float* dst = wa + T.dstOff[b];
    int n = T.n[b];
    for (int i = threadIdx.x; i < n; i += 256)
        dst[i] = isf ? ((const float*)src)[i] : b2f(((const bf16*)src)[i]);
}

// repack Ws1 [64][256] -> fused [128][128]
__global__ __launch_bounds__(256) void repack_ws1_k(const float* __restrict__ s,
                                                    float* __restrict__ d) {
    int id = blockIdx.x * 256 + threadIdx.x;
    if (id >= 128 * 128) return;
    int m = id >> 7, k = id & 127;
    d[id] = (m < 64) ? s[m * 256 + k] : s[(m - 64) * 256 + 128 + k];
}

__global__ __launch_bounds__(256) void conv_i_k(const void* __restrict__ src,
                                                const int* __restrict__ flags,
                                                int* __restrict__ dst, int n) {
    int i = blockIdx.x * 256 + threadIdx.x;
    if (i >= n) return;
    const int* s = (const int*)src;
    dst[i] = flags[1] ? s[2 * i] : s[i];
}

__global__ __launch_bounds__(256) void check_k(const int* __restrict__ ei, int* err) {
    int i = blockIdx.x * 256 + threadIdx.x;
    if (i < 2 * NE && (unsigned)ei[i] >= NN) atomicOr(err, 1);
}
__global__ void finalize_k(const int* err, float* out) {
    if (*err) out[0] = 800.0f;
}

// ---------- ordered-key mapping for fp64 atomic max ----------
__device__ inline unsigned long long d2key(double v) {
    unsigned long long b = __double_as_longlong(v);
    return (b & 0x8000000000000000ULL) ? ~b : (b | 0x8000000000000000ULL);
}
__device__ inline double key2d(unsigned long long k) {
    return (k & 0x8000000000000000ULL) ? __longlong_as_double(k & 0x7fffffffffffffffULL)
                                       : __longlong_as_double(~k);
}

// ---------- CSR build ----------
__global__ __launch_bounds__(256) void deg_dst_k(const int* __restrict__ ei, int* deg) {
    int e = blockIdx.x * 256 + threadIdx.x;
    if (e >= NA) return;
    int d = (e < NE) ? ei[NE + e] : e - NE;
    if ((unsigned)d < NN) atomicAdd(&deg[d], 1);
}
__global__ __launch_bounds__(256) void deg_row_k(const int* __restrict__ ei, int* deg) {
    int e = blockIdx.x * 256 + threadIdx.x;
    if (e >= NE) return;
    int r = ei[e];
    if ((unsigned)r < NN) atomicAdd(&deg[r], 1);
}

__global__ __launch_bounds__(256) void scan1_k(const int* __restrict__ deg,
                                               int* __restrict__ offs,
                                               int* __restrict__ bsums, int n) {
    __shared__ int sh[256];
    int i = blockIdx.x * 256 + threadIdx.x;
    int v = (i < n) ? deg[i] : 0;
    sh[threadIdx.x] = v;
    __syncthreads();
    int acc = v;
    for (int off = 1; off < 256; off <<= 1) {
        int t = (threadIdx.x >= off) ? sh[threadIdx.x - off] : 0;
        __syncthreads();
        acc += t;
        sh[threadIdx.x] = acc;
        __syncthreads();
    }
    if (i < n) offs[i] = acc - v;
    if (threadIdx.x == 255) bsums[blockIdx.x] = acc;
}
__global__ __launch_bounds__(256) void scan2_k(int* __restrict__ bsums, int nb) {
    __shared__ int sh[256];
    int t = threadIdx.x;
    int v = (t < nb) ? bsums[t] : 0;
    sh[t] = v;
    __syncthreads();
    int acc = v;
    for (int off = 1; off < 256; off <<= 1) {
        int x = (t >= off) ? sh[t - off] : 0;
        __syncthreads();
        acc += x;
        sh[t] = acc;
        __syncthreads();
    }
    if (t < nb) bsums[t] = acc - v;
    if (t == nb - 1) bsums[nb] = acc;
}
__global__ __launch_bounds__(256) void scan3_k(int* __restrict__ offs,
                                               const int* __restrict__ bsums, int n, int nb) {
    int i = blockIdx.x * 256 + threadIdx.x;
    if (i < n) offs[i] += bsums[blockIdx.x];
    else if (i == n) offs[n] = bsums[nb];
}
__global__ __launch_bounds__(256) void copy_k(const int* __restrict__ a, int* __restrict__ b,
                                              int n) {
    int i = blockIdx.x * 256 + threadIdx.x;
    if (i < n) b[i] = a[i];
}

__global__ __launch_bounds__(256) void scat_dst_k(const int* __restrict__ ei, int* cur,
                                                  int* __restrict__ entS,
                                                  int* __restrict__ entD) {
    int e = blockIdx.x * 256 + threadIdx.x;
    if (e >= NA) return;
    int s, d;
    if (e < NE) { s = ei[e]; d = ei[NE + e]; }
    else        { s = d = e - NE; }
    if ((unsigned)s >= NN || (unsigned)d >= NN) return;
    int pos = atomicAdd(&cur[d], 1);
    entS[pos] = s;
    entD[pos] = d;
}
__global__ __launch_bounds__(256) void scat_row_k(const int* __restrict__ ei, int* cur,
                                                  int* __restrict__ entc,
                                                  int* __restrict__ ente) {
    int e = blockIdx.x * 256 + threadIdx.x;
    if (e >= NE) return;
    int r = ei[e], c = ei[NE + e];
    if ((unsigned)r >= NN || (unsigned)c >= NN) return;
    int pos = atomicAdd(&cur[r], 1);
    entc[pos] = c;
    ente[pos] = e;
}

// ---------- tiled GEMM: hybrid accumulation; Xs stored TRANSPOSED ([KT][ROWS+4]) ----------
// Hot loop: one b128 Ws read + one b128 Xs broadcast read per k-step (no scalar LDS reads).
// Same values, same accumulation order as before -> bit-identical.
// Compute/store guarded by t < TR*TC (TC=10 has 6 inactive threads).
// ATT requires TC==32 (all threads active).
template <int M, int K, int TC, bool ADD2, int XBN, bool ATT>
__global__ __launch_bounds__(256) void gemm_k(const float* __restrict__ X,
                                              const float* __restrict__ X2,
                                              const float2* __restrict__ ssX,
                                              const float* __restrict__ W, int wstride,
                                              const float* __restrict__ bias,
                                              float* __restrict__ Y, int nrows,
                                              const float* __restrict__ asw,
                                              const float* __restrict__ adw,
                                              double* __restrict__ a_src,
                                              double* __restrict__ a_dst,
                                              unsigned long long* __restrict__ keyM) {
    static_assert(!ATT || TC == 32, "ATT epilogue requires TC==32");
    constexpr int KT = 32;
    constexpr int TR = 256 / TC;
    constexpr int ROWS = TR * 4;          // multiple of 4 -> (ROWS+4)*4B is 16B-aligned
    __shared__ float Ws[KT][M + 4];
    __shared__ float Xs[KT][ROWS + 4];    // transposed tile
    __shared__ double redS[ATT ? NH : 1][8], redD[ATT ? NH : 1][8];

    const int t = threadIdx.x;
    const int lane = t & 63, wv = t >> 6;
    const int row0 = blockIdx.x * ROWS;

    double acc[4][4];
#pragma unroll
    for (int i = 0; i < 4; ++i)
#pragma unroll
        for (int j = 0; j < 4; ++j) acc[i][j] = 0.0;

    for (int k0 = 0; k0 < K; k0 += KT) {
        {
            const int mi = lane >> 3, ki = lane & 7;
            for (int b = wv; b < (M / 8) * (KT / 8); b += 4) {
                int bm = b % (M / 8), bk = b / (M / 8);
                int m = bm * 8 + mi, kk = bk * 8 + ki;
                Ws[kk][m] = W[(size_t)m * wstride + k0 + kk];
            }
        }
        for (int idx = t; idx < ROWS * KT; idx += 256) {
            int r = idx / KT, kk = idx % KT;     // global reads stay kk-coalesced
            int row = row0 + r;
            float v = 0.0f;
            if (row < nrows) {
                v = X[(size_t)row * K + k0 + kk];
                if (ADD2) v += X2[(size_t)row * K + k0 + kk];
                if (XBN) {
                    float2 s = ssX[k0 + kk];
                    v = v * s.x + s.y;
                    if (XBN == 1) v = v > 0.0f ? v : expm1f(v);
                    else          v = v > 0.0f ? v : 0.0f;
                }
            }
            Xs[kk][r] = v;                       // transposed store
        }
        __syncthreads();

        if (t < TR * TC) {
            const int c0 = (t % TC) * 4;
            const int r0 = (t / TC) * 4;
            float facc[4][4];
#pragma unroll
            for (int i = 0; i < 4; ++i)
#pragma unroll
                for (int j = 0; j < 4; ++j) facc[i][j] = 0.0f;
#pragma unroll 4
            for (int kk = 0; kk < KT; ++kk) {
                float4 w = *(const float4*)&Ws[kk][c0];
                float4 x4 = *(const float4*)&Xs[kk][r0];   // broadcast within group
                float xv[4] = {x4.x, x4.y, x4.z, x4.w};
#pragma unroll
                for (int i = 0; i < 4; ++i) {
                    facc[i][0] += xv[i] * w.x;
                    facc[i][1] += xv[i] * w.y;
                    facc[i][2] += xv[i] * w.z;
                    facc[i][3] += xv[i] * w.w;
                }
                if ((kk & 15) == 15) {
#pragma unroll
                    for (int i = 0; i < 4; ++i)
#pragma unroll
                        for (int j = 0; j < 4; ++j) {
                            acc[i][j] += (double)facc[i][j];
                            facc[i][j] = 0.0f;
                        }
                }
            }
        }
        __syncthreads();
    }

    float yv[4][4];
    if (t < TR * TC) {
        const int c0 = (t % TC) * 4;
        const int r0 = (t / TC) * 4;
#pragma unroll
        for (int i = 0; i < 4; ++i) {
            int row = row0 + r0 + i;
#pragma unroll
            for (int j = 0; j < 4; ++j) {
                double v = acc[i][j];
                if (bias) v += (double)bias[c0 + j];
                yv[i][j] = (float)v;
                if (row < nrows) Y[(size_t)row * M + c0 + j] = yv[i][j];
            }
        }
    }

    if constexpr (ATT) {   // TC==32: all 256 threads active
        const int c0 = (t % TC) * 4;
        const int r0 = (t / TC) * 4;
        double ps[4], pd[4];
#pragma unroll
        for (int i = 0; i < 4; ++i) {
            double s = 0.0, d = 0.0;
#pragma unroll
            for (int j = 0; j < 4; ++j) {
                double vv = (double)yv[i][j];
                s += vv * (double)asw[c0 + j];
                d += vv * (double)adw[c0 + j];
            }
            ps[i] = s; pd[i] = d;
        }
#pragma unroll
        for (int off = 1; off <= 2; off <<= 1) {
#pragma unroll
            for (int i = 0; i < 4; ++i) {
                ps[i] += __shfl_xor(ps[i], off, 64);
                pd[i] += __shfl_xor(pd[i], off, 64);
            }
        }
        const int head = (t % TC) >> 2;
        const int rg = t >> 5;
        if ((lane & 3) == 0) {
            double mS = -1e300, mD = -1e300;
#pragma unroll
            for (int i = 0; i < 4; ++i) {
                int row = row0 + r0 + i;
                if (row < nrows) {
                    a_src[(size_t)row * NH + head] = ps[i];
                    a_dst[(size_t)row * NH + head] = pd[i];
                    if (ps[i] > mS) mS = ps[i];
                    if (pd[i] > mD) mD = pd[i];
                }
            }
            redS[head][rg] = mS;
            redD[head][rg] = mD;
        }
        __syncthreads();
        if (t < NH) {
            double mS = -1e300, mD = -1e300;
#pragma unroll
            for (int g = 0; g < 8; ++g) {
                if (redS[t][g] > mS) mS = redS[t][g];
                if (redD[t][g] > mD) mD = redD[t][g];
            }
            atomicMax(&keyM[t], d2key(mS));
            atomicMax(&keyM[NH + t], d2key(mD));
        }
    }
}

// ---------- edge-parallel exp (fp32 expf; x computed fp64) ----------
__global__ __launch_bounds__(256) void edge_exp_k(const int* __restrict__ entS,
                                                  const int* __restrict__ entD,
                                                  const double* __restrict__ a_src,
                                                  const double* __restrict__ a_dst,
                                                  const unsigned long long* __restrict__ keyM,
                                                  float* __restrict__ expv) {
    int id = blockIdx.x * 256 + threadIdx.x;
    if (id >= NA * NH) return;
    int i = id >> 3, hh = id & 7;
    int s = entS[i], d = entD[i];
    double x = a_src[(size_t)s * NH + hh] + a_dst[(size_t)d * NH + hh];
    x = x > 0.0 ? x : 0.2 * x;
    double M = key2d(keyM[hh]) + key2d(keyM[NH + hh]);
    if (M < 0.0) M = 0.0;
    expv[id] = expf((float)(x - M));
}

// ---------- GAT gather: wave per dst, float2 feature packing, unroll-4 ----------
__global__ __launch_bounds__(256) void gat_gather_k(const int* __restrict__ offs,
                                                    const int* __restrict__ ent,
                                                    const float* __restrict__ h,
                                                    const float* __restrict__ expv,
                                                    float* __restrict__ outb) {
    int wv = (blockIdx.x * 256 + threadIdx.x) >> 6;
    int lane = threadIdx.x & 63;
    if (wv >= NN) return;
    const int s0 = offs[wv], s1 = offs[wv + 1];
    const int hh = lane >> 3;
    double acc0 = 0.0, acc1 = 0.0, den = 0.0;
    int i = s0;
    for (; i + 4 <= s1; i += 4) {
        int sA = ent[i], sB = ent[i + 1], sC = ent[i + 2], sD = ent[i + 3];
        float eA = expv[(size_t)(i + 0) * NH + hh];
        float eB = expv[(size_t)(i + 1) * NH + hh];
        float eC = expv[(size_t)(i + 2) * NH + hh];
        float eD = expv[(size_t)(i + 3) * NH + hh];
        float2 a = *(const float2*)&h[(size_t)sA * ND + 2 * lane];
        float2 b = *(const float2*)&h[(size_t)sB * ND + 2 * lane];
        float2 c = *(const float2*)&h[(size_t)sC * ND + 2 * lane];
        float2 d = *(const float2*)&h[(size_t)sD * ND + 2 * lane];
        acc0 += (double)a.x * eA; acc1 += (double)a.y * eA; den += (double)eA;
        acc0 += (double)b.x * eB; acc1 += (double)b.y * eB; den += (double)eB;
        acc0 += (double)c.x * eC; acc1 += (double)c.y * eC; den += (double)eC;
        acc0 += (double)d.x * eD; acc1 += (double)d.y * eD; den += (double)eD;
    }
    for (; i < s1; ++i) {
        int s = ent[i];
        float e = expv[(size_t)i * NH + hh];
        float2 a = *(const float2*)&h[(size_t)s * ND + 2 * lane];
        acc0 += (double)a.x * e; acc1 += (double)a.y * e; den += (double)e;
    }
    double inv = den > 0.0 ? 1.0 / den : 0.0;
    float2 o = make_float2((float)(acc0 * inv), (float)(acc1 * inv));
    *(float2*)&outb[(size_t)wv * ND + 2 * lane] = o;
}

// ---------- one-pass BN stats ----------
template <int M>
__global__ __launch_bounds__(256) void bn_stats1_k(const float* __restrict__ X,
                                                   double* __restrict__ stats, int rpb) {
    constexpr int G = 256 / M;
    __shared__ double sh0[256], sh1[256];
    int f = threadIdx.x % M, g = threadIdx.x / M;
    int r0 = blockIdx.x * rpb;
    int rend = r0 + rpb; if (rend > NN) rend = NN;
    double s = 0.0, s2 = 0.0;
    for (int r = r0 + g; r < rend; r += G) {
        double v = (double)X[(size_t)r * M + f];
        s += v;
        s2 += v * v;
    }
    sh0[threadIdx.x] = s;
    sh1[threadIdx.x] = s2;
    __syncthreads();
    if (g == 0) {
#pragma unroll
        for (int gg = 1; gg < G; ++gg) { s += sh0[gg * M + f]; s2 += sh1[gg * M + f]; }
        atomicAdd(&stats[f], s);
        atomicAdd(&stats[M + f], s2);
    }
}

template <int M>
__global__ void bn_fin_k(const double* __restrict__ stats,
                         const float* __restrict__ gamma, const float* __restrict__ beta,
                         float2* __restrict__ ss) {
    int f = threadIdx.x;
    if (f >= M) return;
    double mu = stats[f] / (double)NN;
    double var = stats[M + f] / (double)NN - mu * mu;
    if (var < 0.0) var = 0.0;
    double sc = (double)gamma[f] / sqrt(var + BN_EPS);
    ss[f] = make_float2((float)sc, (float)((double)beta[f] - mu * sc));
}

template <int M, int ACT>
__global__ __launch_bounds__(256) void bn_apply_ss_k(const float* __restrict__ X,
                                                     const float2* __restrict__ ss,
                                                     float* __restrict__ Y) {
    int id = blockIdx.x * 256 + threadIdx.x;
    if (id >= NN * M) return;
    float2 s = ss[id % M];
    float v = X[id] * s.x + s.y;
    if (ACT == 0) v = v > 0.0f ? v : expm1f(v);
    else          v = v > 0.0f ? v : 0.0f;
    Y[id] = v;
}

// ---------- edge logits: FLAT, 16 lanes/edge, fused pr|pc buffer (coalesced writes) ----------
__global__ __launch_bounds__(256) void edge_logits_k(const int* __restrict__ ei,
                                                     const float4* __restrict__ fused4,
                                                     const float4* __restrict__ bs14,
                                                     const float4* __restrict__ Ws24,
                                                     const float* __restrict__ bs2,
                                                     const void* __restrict__ graw,
                                                     const int* __restrict__ flags,
                                                     float* __restrict__ out) {
    int tid = blockIdx.x * 256 + threadIdx.x;
    int e = tid >> 4;
    int g = tid & 15;
    if (e >= NE) return;
    int r = ei[e], c = ei[NE + e];
    if ((unsigned)r >= NN || (unsigned)c >= NN) return;
    float4 a = fused4[(size_t)r * 32 + g];
    float4 b = fused4[(size_t)c * 32 + 16 + g];
    float4 s1 = bs14[g];
    float4 w2 = Ws24[g];
    double v = 0.0;
    double t0 = (double)a.x + (double)b.x + (double)s1.x; t0 = t0 > 0.0 ? t0 : 0.0;
    double t1 = (double)a.y + (double)b.y + (double)s1.y; t1 = t1 > 0.0 ? t1 : 0.0;
    double t2 = (double)a.z + (double)b.z + (double)s1.z; t2 = t2 > 0.0 ? t2 : 0.0;
    double t3 = (double)a.w + (double)b.w + (double)s1.w; t3 = t3 > 0.0 ? t3 : 0.0;
    v = t0 * (double)w2.x + t1 * (double)w2.y + t2 * (double)w2.z + t3 * (double)w2.w;
#pragma unroll
    for (int off = 8; off > 0; off >>= 1) v += __shfl_xor(v, off, 64);
    if (g == 0) {
        double L = v + (double)bs2[0];
        double g0, g1;
        if (flags[2]) {
            const float* gp = (const float*)graw;
            g0 = (double)gp[2 * e]; g1 = (double)gp[2 * e + 1];
        } else {
            const bf16* gp = (const bf16*)graw;
            g0 = (double)b2f(gp[2 * e]); g1 = (double)b2f(gp[2 * e + 1]);
        }
        out[WOFF + e] = ((L + g1) > g0) ? 1.0f : 0.0f;
        out[LOFF + e] = (float)L;
    }
}

// ---------- sparse agg gather: ballot-compaction + float2 packing + unroll-4 ----------
__global__ __launch_bounds__(256) void agg_gather_k(const int* __restrict__ offs,
                                                    const int* __restrict__ entc,
                                                    const int* __restrict__ ente,
                                                    const float* __restrict__ w,
                                                    const float* __restrict__ hb,
                                                    float* __restrict__ aggF) {
    __shared__ int selBuf[4][64];
    int wv = (blockIdx.x * 256 + threadIdx.x) >> 6;
    int lane = threadIdx.x & 63;
    int wloc = (threadIdx.x >> 6);
    if (wv >= NN) return;
    int* sel = selBuf[wloc];
    const int s0 = offs[wv], s1 = offs[wv + 1];
    double a0 = 0.0, a1 = 0.0;
    for (int base = s0; base < s1; base += 64) {
        int i = base + lane;
        int c = 0;
        bool keep = false;
        if (i < s1) {
            c = entc[i];
            keep = w[ente[i]] > 0.5f;
        }
        unsigned long long m = __ballot(keep);
        int cnt = __popcll(m);
        if (keep) {
            int pos = __popcll(m & ((1ULL << lane) - 1ULL));
            sel[pos] = c;
        }
        __builtin_amdgcn_wave_barrier();
        int j = 0;
        for (; j + 4 <= cnt; j += 4) {
            int cA = sel[j], cB = sel[j + 1], cC = sel[j + 2], cD = sel[j + 3];
            float2 hA = *(const float2*)&hb[(size_t)cA * ND + 2 * lane];
            float2 hB = *(const float2*)&hb[(size_t)cB * ND + 2 * lane];
            float2 hC = *(const float2*)&hb[(size_t)cC * ND + 2 * lane];
            float2 hD = *(const float2*)&hb[(size_t)cD * ND + 2 * lane];
            a0 += (double)hA.x; a1 += (double)hA.y;
            a0 += (double)hB.x; a1 += (double)hB.y;
            a0 += (double)hC.x; a1 += (double)hC.y;
            a0 += (double)hD.x; a1 += (double)hD.y;
        }
        for (; j < cnt; ++j) {
            int c2 = sel[j];
            float2 hv = *(const float2*)&hb[(size_t)c2 * ND + 2 * lane];
            a0 += (double)hv.x; a1 += (double)hv.y;
        }
        __builtin_amdgcn_wave_barrier();
    }
    float2 o = make_float2((float)a0, (float)a1);
    *(float2*)&aggF[(size_t)wv * ND + 2 * lane] = o;
}

// ---------- log-softmax (fp32) ----------
__global__ __launch_bounds__(256) void logsoftmax_k(const float* __restrict__ Y,
                                                    float* __restrict__ out) {
    int wid = (blockIdx.x * 256 + threadIdx.x) / 64;
    int lane = threadIdx.x & 63;
    if (wid >= NN) return;
    float v = (lane < NOUT) ? Y[(size_t)wid * NOUT + lane] : -1e30f;
    float m = v;
#pragma unroll
    for (int off = 32; off > 0; off >>= 1) {
        float o = __shfl_xor(m, off, 64);
        m = m > o ? m : o;
    }
    float ex = (lane < NOUT) ? expf(v - m) : 0.0f;
    float s = ex;
#pragma unroll
    for (int off = 32; off > 0; off >>= 1) s += __shfl_xor(s, off, 64);
    if (lane < NOUT) out[(size_t)wid * NOUT + lane] = v - m - logf(s);
}

extern "C" void kernel_launch(void* const* d_in, const int* in_sizes, int n_in,
                              void* d_out, int out_size, void* d_ws, size_t ws_size,
                              hipStream_t stream) {
    float* out = (float*)d_out;

    static const int EXPS[NIN] = {
        NN * 128, 2 * NE, 2 * NE, 16384, 128, 16384, 128, 128, 128, 128, 128,
        16384, 128, 128, 128, 128, 128, 16384, 64, 64, 1, 8192, 64, 64, 64, 2560, 40 };
    if (n_in != NIN) { sent_k<<<1, 1, 0, stream>>>(out, 700.0f); return; }
    if (out_size != NN * NOUT + 2 * NE) { sent_k<<<1, 1, 0, stream>>>(out, 600.0f); return; }
    for (int i = 0; i < NIN; ++i)
        if (in_sizes[i] != EXPS[i]) {
            sent_k<<<1, 1, 0, stream>>>(out, 1000.0f + 128.0f * i);
            return;
        }

    // ---- workspace layout ----
    char* W = (char*)d_ws;
    double* a_src = (double*)W;                      W += (size_t)NN * NH * 8;
    double* a_dst = (double*)W;                      W += (size_t)NN * NH * 8;
    double* stats = (double*)W;                      W += 256 * 8;
    unsigned long long* keyM = (unsigned long long*)W; W += 16 * 8;
    float2* ss = (float2*)W;                         W += 128 * 8;
    float* F1 = (float*)W;                           W += (size_t)NN * ND * 4;
    float* F2 = (float*)W;                           W += (size_t)NN * ND * 4;
    float* F3 = (float*)W;                           W += (size_t)NN * ND * 4;
    float* F4 = (float*)W;                           W += (size_t)NN * ND * 4;
    float* expv = (float*)W;                         W += (size_t)NA * NH * 4;
    float* wa = (float*)W;
    int off = 0;
    float* aW_res = wa + off; off += 16384;
    float* ab_res = wa + off; off += 128;
    float* aWg1 = wa + off; off += 16384;
    float* aas1 = wa + off; off += 128;
    float* aad1 = wa + off; off += 128;
    float* ag1  = wa + off; off += 128;
    float* abe1 = wa + off; off += 128;
    float* aWg2 = wa + off; off += 16384;
    float* aas2 = wa + off; off += 128;
    float* aad2 = wa + off; off += 128;
    float* ag2  = wa + off; off += 128;
    float* abe2 = wa + off; off += 128;
    float* aWs1 = wa + off; off += 16384;
    float* abs1 = wa + off; off += 64;
    float* aWs2 = wa + off; off += 64;
    float* abs2 = wa + off; off += 4;
    float* aWc1 = wa + off; off += 8192;
    float* abc1 = wa + off; off += 64;
    float* agc  = wa + off; off += 64;
    float* abec = wa + off; off += 64;
    float* aWc2 = wa + off; off += 2560;
    float* abc2 = wa + off; off += 40;
    float* aWs1f = wa + off; off += 16384;
    W = (char*)(wa + off);
    int* ei    = (int*)W;  W += (size_t)2 * NE * 4;
    int* offsG = (int*)W;  W += (size_t)(NN + 1) * 4;
    int* curG  = (int*)W;  W += (size_t)NN * 4;
    int* entG  = (int*)W;  W += (size_t)NA * 4;
    int* entD  = (int*)W;  W += (size_t)NA * 4;
    int* offsR = (int*)W;  W += (size_t)(NN + 1) * 4;
    int* curR  = (int*)W;  W += (size_t)NN * 4;
    int* entRc = (int*)W;  W += (size_t)NE * 4;
    int* entRe = (int*)W;  W += (size_t)NE * 4;
    int* bsums = (int*)W;  W += 260 * 4;
    int* flags = (int*)W;  W += 32 * 4;
    int* errflag = (int*)W; W += 4;
    if ((size_t)(W - (char*)d_ws) > ws_size) { sent_k<<<1, 1, 0, stream>>>(out, 900.0f); return; }

    const int NB = ceil_div(NN, 256);

    // ---- 0) detect & convert ----
    Ptrs P;
    for (int i = 0; i < NIN; ++i) { P.p[i] = d_in[i]; P.n[i] = in_sizes[i]; }
    detect_k<<<NIN, 64, 0, stream>>>(P, flags);
    conv_i_k<<<ceil_div(2 * NE, 256), 256, 0, stream>>>(d_in[1], flags, ei, 2 * NE);
    conv_f_k<<<ceil_div(NN * 128, 256), 256, 0, stream>>>(d_in[0], flags, 0, F2, NN * 128);
    {
        ConvTab T;
        struct { int idx; float* dst; int n; } convs[NCV] = {
            {3, aW_res, 16384}, {4, ab_res, 128}, {5, aWg1, 16384}, {6, aas1, 128},
            {7, aad1, 128}, {9, ag1, 128}, {10, abe1, 128}, {11, aWg2, 16384},
            {12, aas2, 128}, {13, aad2, 128}, {15, ag2, 128}, {16, abe2, 128},
            {17, aWs1, 16384}, {18, abs1, 64}, {19, aWs2, 64}, {20, abs2, 1},
            {21, aWc1, 8192}, {22, abc1, 64}, {23, agc, 64}, {24, abec, 64},
            {25, aWc2, 2560}, {26, abc2, 40},
        };
        for (int i = 0; i < NCV; ++i) {
            T.src[i] = convs[i].idx;
            T.dstOff[i] = (int)(convs[i].dst - wa);
            T.n[i] = convs[i].n;
        }
        conv_all_k<<<NCV, 256, 0, stream>>>(P, T, flags, wa);
    }
    repack_ws1_k<<<ceil_div(16384, 256), 256, 0, stream>>>(aWs1, aWs1f);
    hipMemsetAsync(errflag, 0, 4, stream);
    check_k<<<ceil_div(2 * NE, 256), 256, 0, stream>>>(ei, errflag);

    // ---- CSR builds ----
    hipMemsetAsync(curG, 0, (size_t)NN * 4, stream);
    deg_dst_k<<<ceil_div(NA, 256), 256, 0, stream>>>(ei, curG);
    scan1_k<<<NB, 256, 0, stream>>>(curG, offsG, bsums, NN);
    scan2_k<<<1, 256, 0, stream>>>(bsums, NB);
    scan3_k<<<ceil_div(NN + 1, 256), 256, 0, stream>>>(offsG, bsums, NN, NB);
    copy_k<<<ceil_div(NN, 256), 256, 0, stream>>>(offsG, curG, NN);
    scat_dst_k<<<ceil_div(NA, 256), 256, 0, stream>>>(ei, curG, entG, entD);

    hipMemsetAsync(curR, 0, (size_t)NN * 4, stream);
    deg_row_k<<<ceil_div(NE, 256), 256, 0, stream>>>(ei, curR);
    scan1_k<<<NB, 256, 0, stream>>>(curR, offsR, bsums, NN);
    scan2_k<<<1, 256, 0, stream>>>(bsums, NB);
    scan3_k<<<ceil_div(NN + 1, 256), 256, 0, stream>>>(offsR, bsums, NN, NB);
    copy_k<<<ceil_div(NN, 256), 256, 0, stream>>>(offsR, curR, NN);
    scat_row_k<<<ceil_div(NE, 256), 256, 0, stream>>>(ei, curR, entRc, entRe);

    // ---- 1) x_proj ----
    gemm_k<128, 128, 32, false, 0, false><<<ceil_div(NN, 32), 256, 0, stream>>>(
        F2, nullptr, nullptr, aW_res, 128, ab_res, F1, NN,
        nullptr, nullptr, nullptr, nullptr, nullptr);

    // ---- GAT layer 1 (att scores fused into GEMM epilogue) ----
    hipMemsetAsync(keyM, 0, 16 * 8, stream);
    gemm_k<128, 128, 32, false, 0, true><<<ceil_div(NN, 32), 256, 0, stream>>>(
        F1, nullptr, nullptr, aWg1, 128, nullptr, F2, NN,
        aas1, aad1, a_src, a_dst, keyM);
    edge_exp_k<<<ceil_div(NA * NH, 256), 256, 0, stream>>>(entG, entD, a_src, a_dst, keyM, expv);
    gat_gather_k<<<ceil_div(NN * 64, 256), 256, 0, stream>>>(offsG, entG, F2, expv, F4);
    hipMemsetAsync(stats, 0, 2 * ND * 8, stream);
    bn_stats1_k<128><<<ceil_div(NN, 256), 256, 0, stream>>>(F4, stats, 256);
    bn_fin_k<128><<<1, 128, 0, stream>>>(stats, ag1, abe1, ss);

    // ---- GAT layer 2 (BN1+ELU fused into X staging; att fused in epilogue) ----
    hipMemsetAsync(keyM, 0, 16 * 8, stream);
    gemm_k<128, 128, 32, false, 1, true><<<ceil_div(NN, 32), 256, 0, stream>>>(
        F4, nullptr, ss, aWg2, 128, nullptr, F2, NN,
        aas2, aad2, a_src, a_dst, keyM);
    edge_exp_k<<<ceil_div(NA * NH, 256), 256, 0, stream>>>(entG, entD, a_src, a_dst, keyM, expv);
    gat_gather_k<<<ceil_div(NN * 64, 256), 256, 0, stream>>>(offsG, entG, F2, expv, F4);
    hipMemsetAsync(stats, 0, 2 * ND * 8, stream);
    bn_stats1_k<128><<<ceil_div(NN, 256), 256, 0, stream>>>(F4, stats, 256);
    bn_fin_k<128><<<1, 128, 0, stream>>>(stats, ag2, abe2, ss);
    bn_apply_ss_k<128, 0><<<ceil_div(NN * ND, 256), 256, 0, stream>>>(F4, ss, F3);  // h_base

    // ---- fused pr|pc gemm ----
    gemm_k<128, 128, 32, false, 0, false><<<ceil_div(NN, 32), 256, 0, stream>>>(
        F3, nullptr, nullptr, aWs1f, 128, nullptr, F2, NN,
        nullptr, nullptr, nullptr, nullptr, nullptr);

    // ---- edge logits (flat: coalesced writes) ----
    edge_logits_k<<<ceil_div(NE * 16, 256), 256, 0, stream>>>(
        ei, (const float4*)F2, (const float4*)abs1, (const float4*)aWs2, abs2, d_in[2], flags,
        out);

    // ---- agg (ballot-compacted gather) -> F1 ----
    agg_gather_k<<<ceil_div(NN * 64, 256), 256, 0, stream>>>(offsR, entRc, entRe, out + WOFF,
                                                             F3, F1);

    // ---- t = (h_base + agg) @ Wc1.T + bc1 ----
    gemm_k<64, 128, 16, true, 0, false><<<ceil_div(NN, 64), 256, 0, stream>>>(
        F3, F1, nullptr, aWc1, 128, abc1, F4, NN,
        nullptr, nullptr, nullptr, nullptr, nullptr);

    hipMemsetAsync(stats, 0, 2 * NHID * 8, stream);
    bn_stats1_k<64><<<ceil_div(NN, 256), 256, 0, stream>>>(F4, stats, 256);
    bn_fin_k<64><<<1, 64, 0, stream>>>(stats, agc, abec, ss);

    // ---- logits (BN+ReLU fused into X staging) ----
    float* logits = F4 + (size_t)NN * NHID;
    gemm_k<40, 64, 10, false, 2, false><<<ceil_div(NN, 100), 256, 0, stream>>>(
        F4, nullptr, ss, aWc2, 64, abc2, logits, NN,
        nullptr, nullptr, nullptr, nullptr, nullptr);

    logsoftmax_k<<<ceil_div(NN * 64, 256), 256, 0, stream>>>(logits, out);

    finalize_k<<<1, 1, 0, stream>>>(errflag, out);
}